// Round 8
// baseline (22488.986 us; speedup 1.0000x reference)
//
#include <hip/hip_runtime.h>

// ---------------------------------------------------------------------------
// BiLSTM (T=784, B=512, H=200, D=1) on MI355X — round 8.
//
// Rounds 3-7 verdict: register residency of bulk weights is unreachable
// (allocator spills every pin mix; VGPR_Count pegged at 128/240); only the
// LDS-resident share stopped streaming. Round 8: ALL weights LDS-resident.
// 358KB > 160KB LDS => M-split across 3 cooperating blocks per (dir,slice):
// each owns 17/17/16 tiles (<=122KB LDS) and its 67 hidden units. h (7KB,
// bf16 B-frag layout) round-trips through a double-buffered global exchange
// buffer; a per-group flag barrier (release add + relaxed spin + acquire,
// leader-based -- the hip grid.sync pattern) gates each step. Cooperative
// launch guarantees all 192 blocks co-resident. part=bid/64 puts a group's
// 3 blocks on the same XCD (perf heuristic only, not correctness).
//
// Layout (unchanged):
//  * gate-interleaved M: tile mt row m -> gate q=m&3, hidden j=mt*4+(m>>2).
//  * K padded 200->224 (7 k-tiles); slots 200..204 carry the input path:
//      B[200]=1 (A=Vhi), B[201]=1 (A=Vlo), B[202]=xhi (A=Uhi),
//      B[203]=xhi (A=Ulo), B[204]=xlo (A=Uhi)
//  * hx buffers in B-fragment order; pad slots zeroed by prep_hx, never
//    touched during the scan.
// ---------------------------------------------------------------------------

typedef short short8 __attribute__((ext_vector_type(8)));
typedef float f32x4 __attribute__((ext_vector_type(4)));
typedef unsigned short ushort_t;

#define T_STEPS 784
#define BATCH   512
#define HID     200
#define NKT     7      // K tiles of 32 (224 padded; slots 200..204 = input path)
#define NMT     50     // M tiles of 16 (800 rows, gate-interleaved)
#define THREADS 512    // 8 waves
#define HBUF    3584   // NKT*512 ushorts per hx buffer
#define NGRP    64     // 2 dirs x 32 batch slices
#define WLDS_BYTES (17 * NKT * 512 * 2)   // 121856 B (max tiles per part)

// ws layout (bytes)
#define WS_HSUM 0                         // 784*400*4 = 1254400
#define WS_UV   1254400                   // 2*200*8*4 = 12800
#define WS_WSW  (1254400 + 12800)         // 2*50*7*512*2 = 716800
#define WS_HX   (1254400 + 12800 + 716800)           // 64*2*3584*2 = 917504
#define WS_BAR  (1254400 + 12800 + 716800 + 917504)  // 64*64 = 4096

__device__ __forceinline__ ushort_t f2bf(float f) {
  union { float f; unsigned u; } x; x.f = f;
  return (ushort_t)((x.u + 0x7FFFu + ((x.u >> 16) & 1u)) >> 16);  // RNE
}
__device__ __forceinline__ float bf2f(ushort_t u) {
  union { unsigned u; float f; } x; x.u = (unsigned)u << 16; return x.f;
}

// sum over the 16 lanes of each DPP row; row_shr accumulates toward the TOP
// lane: the full row sum is valid at lane (row base + 15), i.e. bcol==15.
__device__ __forceinline__ float row16_sum(float v) {
  union { float f; int i; } a, b;
  a.f = v;
  b.i = __builtin_amdgcn_update_dpp(0, a.i, 0x118, 0xF, 0xF, true); a.f += b.f; // shr 8
  b.i = __builtin_amdgcn_update_dpp(0, a.i, 0x114, 0xF, 0xF, true); a.f += b.f; // shr 4
  b.i = __builtin_amdgcn_update_dpp(0, a.i, 0x112, 0xF, 0xF, true); a.f += b.f; // shr 2
  b.i = __builtin_amdgcn_update_dpp(0, a.i, 0x111, 0xF, 0xF, true); a.f += b.f; // shr 1
  return a.f;
}

// ---------------------------------------------------------------------------
// prep_uv: uv_g[dir][j][8] = {u_i,u_f,u_g,u_o, v_i,v_f,v_g,v_o}
// ---------------------------------------------------------------------------
__global__ void prep_uv(const float* __restrict__ Wih_f, const float* __restrict__ b_f,
                        const float* __restrict__ Wih_b, const float* __restrict__ b_b,
                        const float* __restrict__ W_in, const float* __restrict__ b_in,
                        float* __restrict__ uv_g) {
  const int dir = blockIdx.x, j = threadIdx.x;
  if (j >= HID) return;
  const float* Wih = dir ? Wih_b : Wih_f;
  const float* b   = dir ? b_b   : b_f;
  for (int q = 0; q < 4; ++q) {
    const int row = q * HID + j;
    const float* wr = Wih + (size_t)row * HID;
    float u = 0.f, v = 0.f;
    for (int k = 0; k < HID; ++k) {
      u = fmaf(wr[k], W_in[k], u);
      v = fmaf(wr[k], b_in[k], v);
    }
    uv_g[(size_t)dir * 1600 + j * 8 + q]     = u;
    uv_g[(size_t)dir * 1600 + j * 8 + 4 + q] = v + b[row];
  }
}

// ---------------------------------------------------------------------------
// prep_w: A-fragments. kt<6: Whh. kt==6: k=192..199 Whh; k=200..204 input path.
//   A-frag lane l: m=l&15 (q=m&3, j=mt*4+(m>>2)), k = kt*32+(l>>4)*8+e
// grid 700 x 64
// ---------------------------------------------------------------------------
__global__ void prep_w(const float* __restrict__ Whh_f, const float* __restrict__ Whh_b,
                       const float* __restrict__ uv_g, ushort_t* __restrict__ w_sw) {
  const int bid = blockIdx.x, lane = threadIdx.x;
  const int dir = bid / (NMT * NKT);
  const int rem = bid % (NMT * NKT);
  const int mt = rem / NKT, kt = rem % NKT;
  const float* W = dir ? Whh_b : Whh_f;
  const int m = lane & 15;
  const int q = m & 3;
  const int j = mt * 4 + (m >> 2);
  const int row = q * HID + j;
  const int grp = lane >> 4;
  short8 v8 = {0, 0, 0, 0, 0, 0, 0, 0};
  if (kt < 6) {
#pragma unroll
    for (int e = 0; e < 8; ++e)
      v8[e] = (short)f2bf(W[(size_t)row * HID + kt * 32 + grp * 8 + e]);
  } else if (grp == 0) {          // k = 192..199
#pragma unroll
    for (int e = 0; e < 8; ++e)
      v8[e] = (short)f2bf(W[(size_t)row * HID + 192 + e]);
  } else if (grp == 1) {          // k = 200..207: input-path slots
    const float U = uv_g[(size_t)dir * 1600 + j * 8 + q];
    const float V = uv_g[(size_t)dir * 1600 + j * 8 + 4 + q];
    const ushort_t vhi = f2bf(V), uhi = f2bf(U);
    v8[0] = (short)vhi;                    // * 1.0
    v8[1] = (short)f2bf(V - bf2f(vhi));    // * 1.0
    v8[2] = (short)uhi;                    // * xhi
    v8[3] = (short)f2bf(U - bf2f(uhi));    // * xhi
    v8[4] = (short)uhi;                    // * xlo
  }
  *(short8*)(w_sw + (size_t)bid * 512 + (size_t)lane * 8) = v8;
}

// ---------------------------------------------------------------------------
// prep_hx: zero both hx buffers of each group; set constant-1 slots (both
// buffers) and x(t0) slots (buffer 0). grid 64 x 64.
// ---------------------------------------------------------------------------
__global__ void prep_hx(const float* __restrict__ x, ushort_t* __restrict__ hx) {
  const int g = blockIdx.x, tid = threadIdx.x;
  const int dir = g & 1, b0 = (g >> 1) * 16;
  ushort_t* hxg = hx + (size_t)g * 2 * HBUF;
  for (int i = tid; i < HBUF; i += 64) ((unsigned*)hxg)[i] = 0;  // both bufs
  __syncthreads();
  if (tid < 16) {
    const int t0 = dir ? T_STEPS - 1 : 0;
    const float x0 = x[(size_t)t0 * BATCH + b0 + tid];
    const ushort_t hi = f2bf(x0);
    const ushort_t lo = f2bf(x0 - bf2f(hi));
    const int sb = 6 * 512 + (16 + tid) * 8;
    hxg[sb + 0] = 0x3F80; hxg[sb + 1] = 0x3F80;          // const-1, buf 0
    hxg[HBUF + sb + 0] = 0x3F80; hxg[HBUF + sb + 1] = 0x3F80;  // buf 1
    hxg[sb + 2] = hi; hxg[sb + 3] = hi; hxg[sb + 4] = lo;       // x(t0), buf 0
  }
}

// ---------------------------------------------------------------------------
// per-cell LSTM update; gates (i,f,g,o) = a[0..3]. 5 exp2 + 2 rcp, clamped.
// hnext is the GLOBAL hx buffer for step t+1.
// ---------------------------------------------------------------------------
__device__ __forceinline__ void cell_update(const f32x4 a, const int haddr,
                                            ushort_t* __restrict__ hnext,
                                            float& c, float& hold) {
  const float L1 = 1.44269504088896340736f;  // log2(e)
  const float ei = __builtin_amdgcn_exp2f(fminf(-L1 * a[0], 30.f));
  const float ef = __builtin_amdgcn_exp2f(fminf(-L1 * a[1], 30.f));
  const float eg = __builtin_amdgcn_exp2f(fminf(-2.f * L1 * a[2], 30.f));
  const float eo = __builtin_amdgcn_exp2f(fminf(-L1 * a[3], 30.f));
  const float pi = 1.f + ei, pf = 1.f + ef, pg = 1.f + eg;
  const float pig = pi * pg;
  const float R1 = __builtin_amdgcn_rcpf(pig * pf);
  const float sf = pig * R1;                    // sigmoid(f)
  const float sitg = (1.f - eg) * pf * R1;      // sigmoid(i)*tanh(g)
  const float cn = fmaf(sf, c, sitg);
  c = cn;
  const float ec = __builtin_amdgcn_exp2f(fminf(-2.f * L1 * cn, 83.f));
  const float R2 = __builtin_amdgcn_rcpf((1.f + ec) * (1.f + eo));
  const float h = (1.f - ec) * R2;              // sigmoid(o)*tanh(c)
  hnext[haddr] = f2bf(h);
  hold = row16_sum(h);  // batch-partial sum (valid at bcol==15)
}

// ---------------------------------------------------------------------------
// the 784-step scan. NT tiles (2 or 3), all LDS-resident.
//  gtb: global tile index of first tile; wl: this wave's LDS tile base.
// ---------------------------------------------------------------------------
template <int NT>
__device__ __forceinline__ void scan_loop(
    const int gtb, const int dir, const int b0, const int lane, const int tid,
    const bool xw, const ushort_t* __restrict__ wl, const float* __restrict__ x,
    float* __restrict__ hsum, ushort_t* __restrict__ hxg,
    unsigned* __restrict__ barp) {
  const int bcol = lane & 15, krow = lane >> 4;

  int haddr[NT];
#pragma unroll
  for (int i = 0; i < NT; ++i) {
    const int j = (gtb + i) * 4 + krow;
    haddr[i] = (j >> 5) * 512 + (bcol | (((j >> 3) & 3) << 4)) * 8 + (j & 7);
  }
  float c[NT], hold[NT];
#pragma unroll
  for (int i = 0; i < NT; ++i) { c[i] = 0.f; hold[i] = 0.f; }

  const int dcol = dir * HID;
  const int jb = gtb * 4 + krow;
  int t_prev = 0, p = 0;

  for (int s = 0; s < T_STEPS; ++s) {
    const int t = dir ? (T_STEPS - 1 - s) : s;

    // deferred hsum atomics from previous step (fire-and-forget; they have a
    // full step of compute + the next fence to complete under)
    if (s > 0 && bcol == 15) {
#pragma unroll
      for (int i = 0; i < NT; ++i)
        atomicAdd(&hsum[(size_t)t_prev * 400 + dcol + jb + 4 * i], hold[i]);
    }

    // B-fragments of [h(t-1); 1; x(t)] from the group's exchange buffer
    const ushort_t* cur = hxg + p * HBUF;
    short8 bf[NKT];
#pragma unroll
    for (int kt = 0; kt < NKT; ++kt)
      bf[kt] = *(const short8*)&cur[kt * 512 + lane * 8];

    ushort_t* nxt = hxg + (p ^ 1) * HBUF;

    // x-writer lanes (part 0, wave 0, krow==1) feed x(t+1) slots of nxt
    if (xw) {
      const int sn = (s + 1 < T_STEPS) ? s + 1 : s;
      const float xn = x[(size_t)(dir ? T_STEPS - 1 - sn : sn) * BATCH + b0 + bcol];
      const ushort_t hi = f2bf(xn);
      const ushort_t lo = f2bf(xn - bf2f(hi));
      const int sb = 6 * 512 + lane * 8;   // lane = 16..31 here
      nxt[sb + 2] = hi;
      nxt[sb + 3] = hi;
      nxt[sb + 4] = lo;
    }

    // MFMA from LDS-resident weights; tiles 0,1 as 2 independent chains
    {
      f32x4 a0 = {0.f, 0.f, 0.f, 0.f}, a1 = {0.f, 0.f, 0.f, 0.f};
#pragma unroll
      for (int kt = 0; kt < NKT; ++kt) {
        const short8 af0 = *(const short8*)&wl[(0 * NKT + kt) * 512 + lane * 8];
        const short8 af1 = *(const short8*)&wl[(1 * NKT + kt) * 512 + lane * 8];
        a0 = __builtin_amdgcn_mfma_f32_16x16x32_bf16(af0, bf[kt], a0, 0, 0, 0);
        a1 = __builtin_amdgcn_mfma_f32_16x16x32_bf16(af1, bf[kt], a1, 0, 0, 0);
      }
      cell_update(a0, haddr[0], nxt, c[0], hold[0]);
      cell_update(a1, haddr[1], nxt, c[1], hold[1]);
    }
    if constexpr (NT == 3) {
      f32x4 a0 = {0.f, 0.f, 0.f, 0.f};
#pragma unroll
      for (int kt = 0; kt < NKT; ++kt) {
        const short8 af = *(const short8*)&wl[(2 * NKT + kt) * 512 + lane * 8];
        a0 = __builtin_amdgcn_mfma_f32_16x16x32_bf16(af, bf[kt], a0, 0, 0, 0);
      }
      cell_update(a0, haddr[2], nxt, c[2], hold[2]);
    }

    t_prev = t;

    // 3-block group barrier (skip after the last step)
    if (s + 1 < T_STEPS) {
      __threadfence();       // publish my hx/nxt stores (vmcnt0 + L2 wb)
      __syncthreads();       // whole block done writing
      if (tid == 0) {
        __hip_atomic_fetch_add(barp, 1u, __ATOMIC_RELEASE, __HIP_MEMORY_SCOPE_AGENT);
        const unsigned tgt = 3u * (unsigned)(s + 1);
        while (__hip_atomic_load(barp, __ATOMIC_RELAXED, __HIP_MEMORY_SCOPE_AGENT) < tgt)
          __builtin_amdgcn_s_sleep(8);
        (void)__hip_atomic_load(barp, __ATOMIC_ACQUIRE, __HIP_MEMORY_SCOPE_AGENT);
      }
      __syncthreads();       // release whole block; acquire invalidated caches
    }
    p ^= 1;
  }
  if (bcol == 15) {
#pragma unroll
    for (int i = 0; i < NT; ++i)
      atomicAdd(&hsum[(size_t)t_prev * 400 + dcol + jb + 4 * i], hold[i]);
  }
}

// ---------------------------------------------------------------------------
// main scan kernel: 192 blocks = 3 parts x 64 groups (part = bid/64 so a
// group's blocks share an XCD under round-robin dispatch). 512 threads.
// Dynamic LDS: this part's weight tiles only (<= 121856 B).
// ---------------------------------------------------------------------------
__global__ __launch_bounds__(THREADS) void lstm_main(
    const float* __restrict__ x, const ushort_t* __restrict__ w_sw,
    ushort_t* __restrict__ hx, unsigned* __restrict__ bar,
    float* __restrict__ hsum) {
  extern __shared__ __align__(16) ushort_t wlds[];

  const int bid = blockIdx.x;
  const int part = bid >> 6;        // 0,1,2
  const int g = bid & 63;           // (slice<<1)|dir
  const int dir = g & 1;
  const int b0 = (g >> 1) * 16;
  const int tid = threadIdx.x;
  const int lane = tid & 63;
  const int wv = tid >> 6;

  const int tb = part * 17;                       // part2 -> 34
  const int ntile = (part < 2) ? 17 : 16;

  // stage this part's tiles into LDS (once)
  const ushort_t* wg = w_sw + (size_t)dir * NMT * NKT * 512 + (size_t)tb * NKT * 512;
  for (int i = tid; i < ntile * (NKT * 256); i += THREADS)   // uint granularity
    ((unsigned*)wlds)[i] = ((const unsigned*)wg)[i];
  __syncthreads();

  ushort_t* hxg = hx + (size_t)g * 2 * HBUF;
  unsigned* barp = bar + g * 16;    // 64B padded per group

  // wave -> local tiles: 17 tiles: w0..w6 get 2, w7 gets 3; 16 tiles: 2 each
  const int ltb = (ntile == 17 && wv == 7) ? 14 : 2 * wv;
  const bool xw = (part == 0) & (wv == 0) & ((lane >> 4) == 1);
  const ushort_t* wl = wlds + (size_t)ltb * NKT * 512;

  if (ntile == 17 && wv == 7)
    scan_loop<3>(tb + ltb, dir, b0, lane, tid, xw, wl, x, hsum, hxg, barp);
  else
    scan_loop<2>(tb + ltb, dir, b0, lane, tid, xw, wl, x, hsum, hxg, barp);
}

// ---------------------------------------------------------------------------
// out[t][o] = b_fc[o] + (1/512) * sum_col hsum[t][col] * W_fc[o][col]
// ---------------------------------------------------------------------------
__global__ void out_proj(const float* __restrict__ hsum, const float* __restrict__ Wfc,
                         const float* __restrict__ bfc, float* __restrict__ out) {
  const int t = blockIdx.x, tid = threadIdx.x;
  float a[10] = {0.f, 0.f, 0.f, 0.f, 0.f, 0.f, 0.f, 0.f, 0.f, 0.f};
  for (int col = tid; col < 400; col += 256) {
    const float hv = hsum[(size_t)t * 400 + col] * (1.f / 512.f);
#pragma unroll
    for (int o = 0; o < 10; ++o) a[o] = fmaf(hv, Wfc[o * 400 + col], a[o]);
  }
#pragma unroll
  for (int o = 0; o < 10; ++o) {
    float v = a[o];
    for (int m = 32; m; m >>= 1) v += __shfl_xor(v, m);
    a[o] = v;
  }
  __shared__ float red[4][10];
  if ((tid & 63) == 0)
#pragma unroll
    for (int o = 0; o < 10; ++o) red[tid >> 6][o] = a[o];
  __syncthreads();
  if (tid < 10)
    out[t * 10 + tid] = bfc[tid] + red[0][tid] + red[1][tid] + red[2][tid] + red[3][tid];
}

extern "C" void kernel_launch(void* const* d_in, const int* in_sizes, int n_in,
                              void* d_out, int out_size, void* d_ws, size_t ws_size,
                              hipStream_t stream) {
  const float* x     = (const float*)d_in[0];
  const float* W_in  = (const float*)d_in[1];
  const float* b_in  = (const float*)d_in[2];
  const float* Wih_f = (const float*)d_in[3];
  const float* Whh_f = (const float*)d_in[4];
  const float* b_f   = (const float*)d_in[5];
  const float* Wih_b = (const float*)d_in[6];
  const float* Whh_b = (const float*)d_in[7];
  const float* b_b   = (const float*)d_in[8];
  const float* W_fc  = (const float*)d_in[9];
  const float* b_fc  = (const float*)d_in[10];
  float* out = (float*)d_out;

  char* ws = (char*)d_ws;
  float*    hsum = (float*)(ws + WS_HSUM);
  float*    uv_g = (float*)(ws + WS_UV);
  ushort_t* w_sw = (ushort_t*)(ws + WS_WSW);
  ushort_t* hx   = (ushort_t*)(ws + WS_HX);
  unsigned* bar  = (unsigned*)(ws + WS_BAR);

  hipFuncSetAttribute((const void*)lstm_main,
                      hipFuncAttributeMaxDynamicSharedMemorySize, WLDS_BYTES);

  hipMemsetAsync(hsum, 0, (size_t)T_STEPS * 400 * sizeof(float), stream);
  hipMemsetAsync(bar, 0, NGRP * 64, stream);
  prep_uv<<<2, 256, 0, stream>>>(Wih_f, b_f, Wih_b, b_b, W_in, b_in, uv_g);
  prep_w<<<2 * NMT * NKT, 64, 0, stream>>>(Whh_f, Whh_b, uv_g, w_sw);
  prep_hx<<<NGRP, 64, 0, stream>>>(x, hx);

  void* args[] = {(void*)&x, (void*)&w_sw, (void*)&hx, (void*)&bar, (void*)&hsum};
  hipLaunchCooperativeKernel((const void*)lstm_main, dim3(192), dim3(THREADS),
                             args, WLDS_BYTES, stream);

  out_proj<<<T_STEPS, 256, 0, stream>>>(hsum, W_fc, b_fc, out);
}

// Round 10
// 1835.232 us; speedup vs baseline: 12.2540x; 12.2540x over previous
//
#include <hip/hip_runtime.h>

// ---------------------------------------------------------------------------
// BiLSTM (T=784, B=512, H=200, D=1) on MI355X — round 10.
//
// Round-9 lesson: clobber lists don't create liveness. The 18 LDS-tile
// BUILTIN MFMAs let the allocator place their accumulators ("av" class) in
// a0..a111 between my asm statements — corrupting the pinned weights
// (absmax 6.3e-2). Fix (single variable vs r9): LDS-tile MFMAs become
// inline-asm with "+v" accumulators and "v" operands, so NOTHING in the
// loop can legally use AGPRs; a0..a111 stay untouched between my asms.
// Arch ask ~130 <= 144 (= 256 unified - 112 AGPR @ launch_bounds(512,2)).
//
// Structure (round 7/9): 64 blocks (dir, 16-batch slice), 512 thr, 8 waves.
// Wave w: 4 weight tiles in fixed AGPRs a0..a111 + 2-3 tiles in LDS.
// h in LDS (B-frag order, dbuf); input path folded into K-pad slots 200..204;
// gate-interleaved M (tile mt row m -> gate m&3, hidden mt*4+(m>>2)).
// Hazards: s_nop 1 before each chain's first MFMA (VALU init -> SrcC),
// 2x s_nop 7 after each chain's last MFMA (MFMA write -> VALU read),
// 2x s_nop 7 after the accvgpr_write pin block.
// ---------------------------------------------------------------------------

typedef short short8 __attribute__((ext_vector_type(8)));
typedef float f32x4 __attribute__((ext_vector_type(4)));
typedef unsigned short ushort_t;

#define T_STEPS 784
#define BATCH   512
#define HID     200
#define NKT     7
#define NMT     50
#define THREADS 512
#define HBUF    3584
#define NLDST   18
#define DYN_LDS (2 * HBUF * 2 + NLDST * NKT * 512 * 2)  // 143360 B

#define WS_HSUM 0
#define WS_UV   1254400
#define WS_WSW  (1254400 + 12800)

__device__ __forceinline__ ushort_t f2bf(float f) {
  union { float f; unsigned u; } x; x.f = f;
  return (ushort_t)((x.u + 0x7FFFu + ((x.u >> 16) & 1u)) >> 16);  // RNE
}
__device__ __forceinline__ float bf2f(ushort_t u) {
  union { unsigned u; float f; } x; x.u = (unsigned)u << 16; return x.f;
}

__device__ __forceinline__ float row16_sum(float v) {
  union { float f; int i; } a, b;
  a.f = v;
  b.i = __builtin_amdgcn_update_dpp(0, a.i, 0x118, 0xF, 0xF, true); a.f += b.f;
  b.i = __builtin_amdgcn_update_dpp(0, a.i, 0x114, 0xF, 0xF, true); a.f += b.f;
  b.i = __builtin_amdgcn_update_dpp(0, a.i, 0x112, 0xF, 0xF, true); a.f += b.f;
  b.i = __builtin_amdgcn_update_dpp(0, a.i, 0x111, 0xF, 0xF, true); a.f += b.f;
  return a.f;  // row sum valid at bcol==15
}

// --- AGPR pin: one 4-dword fragment of tile T, k-tile K into fixed a-regs
#define PIN1(T, K, N0, N1, N2, N3)                                            \
  {                                                                           \
    union { short8 s; unsigned u[4]; } cv;                                    \
    cv.s = *(const short8*)(wg +                                              \
        ((size_t)((rbase + (T)) * NKT + (K))) * 512 + lane * 8);              \
    asm volatile("v_accvgpr_write_b32 a" #N0 ", %0\n\t"                       \
                 "v_accvgpr_write_b32 a" #N1 ", %1\n\t"                       \
                 "v_accvgpr_write_b32 a" #N2 ", %2\n\t"                       \
                 "v_accvgpr_write_b32 a" #N3 ", %3"                           \
                 :: "v"(cv.u[0]), "v"(cv.u[1]), "v"(cv.u[2]), "v"(cv.u[3])    \
                 : "a" #N0, "a" #N1, "a" #N2, "a" #N3);                       \
  }

// --- inline-asm MFMA, A from fixed AGPRs
#define MF(N0, N1, N2, N3, ACC, B)                                            \
  asm volatile("v_mfma_f32_16x16x32_bf16 %0, a[" #N0 ":" #N3 "], %1, %0"      \
               : "+v"(ACC) : "v"(B)                                           \
               : "a" #N0, "a" #N1, "a" #N2, "a" #N3)
#define MFS(N0, N1, N2, N3, ACC, B)                                           \
  asm volatile("s_nop 1\n\t"                                                  \
               "v_mfma_f32_16x16x32_bf16 %0, a[" #N0 ":" #N3 "], %1, %0"      \
               : "+v"(ACC) : "v"(B)                                           \
               : "a" #N0, "a" #N1, "a" #N2, "a" #N3)
#define MFE(N0, N1, N2, N3, ACC, B)                                           \
  asm volatile("v_mfma_f32_16x16x32_bf16 %0, a[" #N0 ":" #N3 "], %1, %0\n\t"  \
               "s_nop 7\n\ts_nop 7"                                           \
               : "+v"(ACC) : "v"(B)                                           \
               : "a" #N0, "a" #N1, "a" #N2, "a" #N3)

// --- inline-asm MFMA, all-VGPR (LDS-resident tiles) — keeps AGPRs untouched
#define MFV(ACC, A, B)                                                        \
  asm volatile("v_mfma_f32_16x16x32_bf16 %0, %1, %2, %0"                      \
               : "+v"(ACC) : "v"(A), "v"(B))
#define MFVS(ACC, A, B)                                                       \
  asm volatile("s_nop 1\n\t"                                                  \
               "v_mfma_f32_16x16x32_bf16 %0, %1, %2, %0"                      \
               : "+v"(ACC) : "v"(A), "v"(B))
#define MFVE(ACC, A, B)                                                       \
  asm volatile("v_mfma_f32_16x16x32_bf16 %0, %1, %2, %0\n\t"                  \
               "s_nop 7\n\ts_nop 7"                                           \
               : "+v"(ACC) : "v"(A), "v"(B))

// ---------------------------------------------------------------------------
__global__ void prep_uv(const float* __restrict__ Wih_f, const float* __restrict__ b_f,
                        const float* __restrict__ Wih_b, const float* __restrict__ b_b,
                        const float* __restrict__ W_in, const float* __restrict__ b_in,
                        float* __restrict__ uv_g) {
  const int dir = blockIdx.x, j = threadIdx.x;
  if (j >= HID) return;
  const float* Wih = dir ? Wih_b : Wih_f;
  const float* b   = dir ? b_b   : b_f;
  for (int q = 0; q < 4; ++q) {
    const int row = q * HID + j;
    const float* wr = Wih + (size_t)row * HID;
    float u = 0.f, v = 0.f;
    for (int k = 0; k < HID; ++k) {
      u = fmaf(wr[k], W_in[k], u);
      v = fmaf(wr[k], b_in[k], v);
    }
    uv_g[(size_t)dir * 1600 + j * 8 + q]     = u;
    uv_g[(size_t)dir * 1600 + j * 8 + 4 + q] = v + b[row];
  }
}

// ---------------------------------------------------------------------------
__global__ void prep_w(const float* __restrict__ Whh_f, const float* __restrict__ Whh_b,
                       const float* __restrict__ uv_g, ushort_t* __restrict__ w_sw) {
  const int bid = blockIdx.x, lane = threadIdx.x;
  const int dir = bid / (NMT * NKT);
  const int rem = bid % (NMT * NKT);
  const int mt = rem / NKT, kt = rem % NKT;
  const float* W = dir ? Whh_b : Whh_f;
  const int m = lane & 15;
  const int q = m & 3;
  const int j = mt * 4 + (m >> 2);
  const int row = q * HID + j;
  const int grp = lane >> 4;
  short8 v8 = {0, 0, 0, 0, 0, 0, 0, 0};
  if (kt < 6) {
#pragma unroll
    for (int e = 0; e < 8; ++e)
      v8[e] = (short)f2bf(W[(size_t)row * HID + kt * 32 + grp * 8 + e]);
  } else if (grp == 0) {
#pragma unroll
    for (int e = 0; e < 8; ++e)
      v8[e] = (short)f2bf(W[(size_t)row * HID + 192 + e]);
  } else if (grp == 1) {
    const float U = uv_g[(size_t)dir * 1600 + j * 8 + q];
    const float V = uv_g[(size_t)dir * 1600 + j * 8 + 4 + q];
    const ushort_t vhi = f2bf(V), uhi = f2bf(U);
    v8[0] = (short)vhi;
    v8[1] = (short)f2bf(V - bf2f(vhi));
    v8[2] = (short)uhi;
    v8[3] = (short)f2bf(U - bf2f(uhi));
    v8[4] = (short)uhi;
  }
  *(short8*)(w_sw + (size_t)bid * 512 + (size_t)lane * 8) = v8;
}

// ---------------------------------------------------------------------------
__device__ __forceinline__ void cell_update(const f32x4 a, const int haddr,
                                            ushort_t* __restrict__ hnext,
                                            float& c, float& hold) {
  const float L1 = 1.44269504088896340736f;
  const float ei = __builtin_amdgcn_exp2f(fminf(-L1 * a[0], 30.f));
  const float ef = __builtin_amdgcn_exp2f(fminf(-L1 * a[1], 30.f));
  const float eg = __builtin_amdgcn_exp2f(fminf(-2.f * L1 * a[2], 30.f));
  const float eo = __builtin_amdgcn_exp2f(fminf(-L1 * a[3], 30.f));
  const float pi = 1.f + ei, pf = 1.f + ef, pg = 1.f + eg;
  const float pig = pi * pg;
  const float R1 = __builtin_amdgcn_rcpf(pig * pf);
  const float sf = pig * R1;
  const float sitg = (1.f - eg) * pf * R1;
  const float cn = fmaf(sf, c, sitg);
  c = cn;
  const float ec = __builtin_amdgcn_exp2f(fminf(-2.f * L1 * cn, 83.f));
  const float R2 = __builtin_amdgcn_rcpf((1.f + ec) * (1.f + eo));
  const float h = (1.f - ec) * R2;
  hnext[haddr] = f2bf(h);
  hold = row16_sum(h);
}

// ---------------------------------------------------------------------------
// 784-step scan: 4 AGPR tiles (a0..a111) at rbase.., NLDS LDS tiles at lfirst.
// ---------------------------------------------------------------------------
template <int NLDS>
__device__ __forceinline__ void scan_loop(
    const int rbase, const int lfirst, const int dir, const int b0,
    const int lane, const int wv, const ushort_t* __restrict__ wg,
    const float* __restrict__ x, float* __restrict__ hsum,
    ushort_t* __restrict__ h_lds, const ushort_t* __restrict__ w_lds_my) {
  constexpr int NREG = 4;
  constexpr int NT = NREG + NLDS;
  const int bcol = lane & 15, krow = lane >> 4;
  const bool xw = (wv == 0) & (krow == 1);

  // pin 4 tiles into fixed AGPRs a0..a111 (28 dwords per tile)
  PIN1(0, 0,  0,  1,  2,  3)  PIN1(0, 1,  4,  5,  6,  7)
  PIN1(0, 2,  8,  9, 10, 11)  PIN1(0, 3, 12, 13, 14, 15)
  PIN1(0, 4, 16, 17, 18, 19)  PIN1(0, 5, 20, 21, 22, 23)
  PIN1(0, 6, 24, 25, 26, 27)
  PIN1(1, 0, 28, 29, 30, 31)  PIN1(1, 1, 32, 33, 34, 35)
  PIN1(1, 2, 36, 37, 38, 39)  PIN1(1, 3, 40, 41, 42, 43)
  PIN1(1, 4, 44, 45, 46, 47)  PIN1(1, 5, 48, 49, 50, 51)
  PIN1(1, 6, 52, 53, 54, 55)
  PIN1(2, 0, 56, 57, 58, 59)  PIN1(2, 1, 60, 61, 62, 63)
  PIN1(2, 2, 64, 65, 66, 67)  PIN1(2, 3, 68, 69, 70, 71)
  PIN1(2, 4, 72, 73, 74, 75)  PIN1(2, 5, 76, 77, 78, 79)
  PIN1(2, 6, 80, 81, 82, 83)
  PIN1(3, 0, 84, 85, 86, 87)  PIN1(3, 1, 88, 89, 90, 91)
  PIN1(3, 2, 92, 93, 94, 95)  PIN1(3, 3, 96, 97, 98, 99)
  PIN1(3, 4, 100, 101, 102, 103)  PIN1(3, 5, 104, 105, 106, 107)
  PIN1(3, 6, 108, 109, 110, 111)
  asm volatile("s_nop 7\n\ts_nop 7");  // accvgpr_write -> mfma-read spacing

  int haddr[NT];
#pragma unroll
  for (int i = 0; i < NT; ++i) {
    const int tile = (i < NREG) ? rbase + i : lfirst + (i - NREG);
    const int j = tile * 4 + krow;
    haddr[i] = (j >> 5) * 512 + (bcol | (((j >> 3) & 3) << 4)) * 8 + (j & 7);
  }
  float c[NT], hold[NT];
#pragma unroll
  for (int i = 0; i < NT; ++i) { c[i] = 0.f; hold[i] = 0.f; }

  const int dcol = dir * HID;
  const int jb = rbase * 4 + krow;
  const int jl = lfirst * 4 + krow;
  int t_prev = 0, cur = 0;

  for (int s = 0; s < T_STEPS; ++s) {
    const int t = dir ? (T_STEPS - 1 - s) : s;

    if (s > 0 && bcol == 15) {
#pragma unroll
      for (int i = 0; i < NREG; ++i)
        atomicAdd(&hsum[(size_t)t_prev * 400 + dcol + jb + 4 * i], hold[i]);
#pragma unroll
      for (int i = 0; i < NLDS; ++i)
        atomicAdd(&hsum[(size_t)t_prev * 400 + dcol + jl + 4 * i], hold[NREG + i]);
    }

    const int sn = (s + 1 < T_STEPS) ? s + 1 : s;
    float xn = 0.f;
    if (xw) xn = x[(size_t)(dir ? T_STEPS - 1 - sn : sn) * BATCH + b0 + bcol];

    short8 bf[NKT];
#pragma unroll
    for (int kt = 0; kt < NKT; ++kt)
      bf[kt] = *(const short8*)&h_lds[cur * HBUF + kt * 512 + lane * 8];

    ushort_t* hnext = h_lds + (cur ^ 1) * HBUF;

    if (xw) {
      const ushort_t hi = f2bf(xn);
      const ushort_t lo = f2bf(xn - bf2f(hi));
      const int sb = 6 * 512 + lane * 8;
      hnext[sb + 2] = hi;
      hnext[sb + 3] = hi;
      hnext[sb + 4] = lo;
    }

    // AGPR tiles 0,1 (two independent chains)
    {
      f32x4 a0 = {0.f, 0.f, 0.f, 0.f}, a1 = {0.f, 0.f, 0.f, 0.f};
      MFS(0, 1, 2, 3, a0, bf[0]);      MFS(28, 29, 30, 31, a1, bf[0]);
      MF(4, 5, 6, 7, a0, bf[1]);       MF(32, 33, 34, 35, a1, bf[1]);
      MF(8, 9, 10, 11, a0, bf[2]);     MF(36, 37, 38, 39, a1, bf[2]);
      MF(12, 13, 14, 15, a0, bf[3]);   MF(40, 41, 42, 43, a1, bf[3]);
      MF(16, 17, 18, 19, a0, bf[4]);   MF(44, 45, 46, 47, a1, bf[4]);
      MF(20, 21, 22, 23, a0, bf[5]);   MF(48, 49, 50, 51, a1, bf[5]);
      MFE(24, 25, 26, 27, a0, bf[6]);  MFE(52, 53, 54, 55, a1, bf[6]);
      cell_update(a0, haddr[0], hnext, c[0], hold[0]);
      cell_update(a1, haddr[1], hnext, c[1], hold[1]);
    }
    // AGPR tiles 2,3
    {
      f32x4 a0 = {0.f, 0.f, 0.f, 0.f}, a1 = {0.f, 0.f, 0.f, 0.f};
      MFS(56, 57, 58, 59, a0, bf[0]);  MFS(84, 85, 86, 87, a1, bf[0]);
      MF(60, 61, 62, 63, a0, bf[1]);   MF(88, 89, 90, 91, a1, bf[1]);
      MF(64, 65, 66, 67, a0, bf[2]);   MF(92, 93, 94, 95, a1, bf[2]);
      MF(68, 69, 70, 71, a0, bf[3]);   MF(96, 97, 98, 99, a1, bf[3]);
      MF(72, 73, 74, 75, a0, bf[4]);   MF(100, 101, 102, 103, a1, bf[4]);
      MF(76, 77, 78, 79, a0, bf[5]);   MF(104, 105, 106, 107, a1, bf[5]);
      MFE(80, 81, 82, 83, a0, bf[6]);  MFE(108, 109, 110, 111, a1, bf[6]);
      cell_update(a0, haddr[2], hnext, c[2], hold[2]);
      cell_update(a1, haddr[3], hnext, c[3], hold[3]);
    }
    // LDS tiles — inline-asm all-VGPR MFMA (no AGPR use anywhere here)
#pragma unroll
    for (int p = 0; p + 1 < NLDS; p += 2) {
      const int i0 = NREG + p, i1 = NREG + p + 1;
      f32x4 a0 = {0.f, 0.f, 0.f, 0.f}, a1 = {0.f, 0.f, 0.f, 0.f};
      {
        const short8 af0 = *(const short8*)&w_lds_my[((p)     * NKT + 0) * 512 + lane * 8];
        const short8 af1 = *(const short8*)&w_lds_my[((p + 1) * NKT + 0) * 512 + lane * 8];
        MFVS(a0, af0, bf[0]);  MFVS(a1, af1, bf[0]);
      }
#pragma unroll
      for (int kt = 1; kt < NKT - 1; ++kt) {
        const short8 af0 = *(const short8*)&w_lds_my[((p)     * NKT + kt) * 512 + lane * 8];
        const short8 af1 = *(const short8*)&w_lds_my[((p + 1) * NKT + kt) * 512 + lane * 8];
        MFV(a0, af0, bf[kt]);  MFV(a1, af1, bf[kt]);
      }
      {
        const short8 af0 = *(const short8*)&w_lds_my[((p)     * NKT + 6) * 512 + lane * 8];
        const short8 af1 = *(const short8*)&w_lds_my[((p + 1) * NKT + 6) * 512 + lane * 8];
        MFVE(a0, af0, bf[6]);  MFVE(a1, af1, bf[6]);
      }
      cell_update(a0, haddr[i0], hnext, c[i0], hold[i0]);
      cell_update(a1, haddr[i1], hnext, c[i1], hold[i1]);
    }
    if constexpr (NLDS & 1) {
      constexpr int p = NLDS - 1;
      const int i0 = NREG + p;
      f32x4 a0 = {0.f, 0.f, 0.f, 0.f};
      {
        const short8 af = *(const short8*)&w_lds_my[(p * NKT + 0) * 512 + lane * 8];
        MFVS(a0, af, bf[0]);
      }
#pragma unroll
      for (int kt = 1; kt < NKT - 1; ++kt) {
        const short8 af = *(const short8*)&w_lds_my[(p * NKT + kt) * 512 + lane * 8];
        MFV(a0, af, bf[kt]);
      }
      {
        const short8 af = *(const short8*)&w_lds_my[(p * NKT + 6) * 512 + lane * 8];
        MFVE(a0, af, bf[6]);
      }
      cell_update(a0, haddr[i0], hnext, c[i0], hold[i0]);
    }

    t_prev = t;
    __syncthreads();
    cur ^= 1;
  }
  if (bcol == 15) {
#pragma unroll
    for (int i = 0; i < NREG; ++i)
      atomicAdd(&hsum[(size_t)t_prev * 400 + dcol + jb + 4 * i], hold[i]);
#pragma unroll
    for (int i = 0; i < NLDS; ++i)
      atomicAdd(&hsum[(size_t)t_prev * 400 + dcol + jl + 4 * i], hold[NREG + i]);
  }
}

// ---------------------------------------------------------------------------
// main scan kernel: 64 blocks, 512 threads, 2 waves/SIMD (112 AGPR + ~140 VGPR)
// ---------------------------------------------------------------------------
__global__ __launch_bounds__(THREADS, 2) void lstm_main(
    const float* __restrict__ x, const ushort_t* __restrict__ w_sw,
    float* __restrict__ hsum) {
  extern __shared__ __align__(16) ushort_t dynlds[];
  ushort_t* h_lds = dynlds;
  ushort_t* w_lds = dynlds + 2 * HBUF;

  const int tid = threadIdx.x;
  const int lane = tid & 63;
  const int wv = tid >> 6;
  const int dir = blockIdx.x & 1;
  const int b0 = (blockIdx.x >> 1) * 16;

  const ushort_t* wg = w_sw + (size_t)dir * NMT * NKT * 512;

  for (int i = tid; i < HBUF; i += THREADS) ((unsigned*)h_lds)[i] = 0;
  for (int i = tid; i < NLDST * NKT * 64; i += THREADS)
    *(short8*)&w_lds[(size_t)i * 8] =
        *(const short8*)(wg + (size_t)32 * NKT * 512 + (size_t)i * 8);
  __syncthreads();

  if (tid < 16) {
    const int t0 = dir ? T_STEPS - 1 : 0;
    const float x0 = x[(size_t)t0 * BATCH + b0 + tid];
    const ushort_t hi = f2bf(x0);
    const ushort_t lo = f2bf(x0 - bf2f(hi));
    const int sb = 6 * 512 + (16 + tid) * 8;
    h_lds[sb + 0] = 0x3F80; h_lds[sb + 1] = 0x3F80;
    h_lds[HBUF + sb + 0] = 0x3F80; h_lds[HBUF + sb + 1] = 0x3F80;
    h_lds[sb + 2] = hi; h_lds[sb + 3] = hi; h_lds[sb + 4] = lo;
  }
  __syncthreads();

  const int rbase = 4 * wv;
  const int lfirst = (wv < 6) ? (32 + 2 * wv) : (44 + 3 * (wv - 6));
  const ushort_t* wl = w_lds + (size_t)(lfirst - 32) * NKT * 512;
  if (wv < 6)
    scan_loop<2>(rbase, lfirst, dir, b0, lane, wv, wg, x, hsum, h_lds, wl);
  else
    scan_loop<3>(rbase, lfirst, dir, b0, lane, wv, wg, x, hsum, h_lds, wl);
}

// ---------------------------------------------------------------------------
__global__ void out_proj(const float* __restrict__ hsum, const float* __restrict__ Wfc,
                         const float* __restrict__ bfc, float* __restrict__ out) {
  const int t = blockIdx.x, tid = threadIdx.x;
  float a[10] = {0.f, 0.f, 0.f, 0.f, 0.f, 0.f, 0.f, 0.f, 0.f, 0.f};
  for (int col = tid; col < 400; col += 256) {
    const float hv = hsum[(size_t)t * 400 + col] * (1.f / 512.f);
#pragma unroll
    for (int o = 0; o < 10; ++o) a[o] = fmaf(hv, Wfc[o * 400 + col], a[o]);
  }
#pragma unroll
  for (int o = 0; o < 10; ++o) {
    float v = a[o];
    for (int m = 32; m; m >>= 1) v += __shfl_xor(v, m);
    a[o] = v;
  }
  __shared__ float red[4][10];
  if ((tid & 63) == 0)
#pragma unroll
    for (int o = 0; o < 10; ++o) red[tid >> 6][o] = a[o];
  __syncthreads();
  if (tid < 10)
    out[t * 10 + tid] = bfc[tid] + red[0][tid] + red[1][tid] + red[2][tid] + red[3][tid];
}

extern "C" void kernel_launch(void* const* d_in, const int* in_sizes, int n_in,
                              void* d_out, int out_size, void* d_ws, size_t ws_size,
                              hipStream_t stream) {
  const float* x     = (const float*)d_in[0];
  const float* W_in  = (const float*)d_in[1];
  const float* b_in  = (const float*)d_in[2];
  const float* Wih_f = (const float*)d_in[3];
  const float* Whh_f = (const float*)d_in[4];
  const float* b_f   = (const float*)d_in[5];
  const float* Wih_b = (const float*)d_in[6];
  const float* Whh_b = (const float*)d_in[7];
  const float* b_b   = (const float*)d_in[8];
  const float* W_fc  = (const float*)d_in[9];
  const float* b_fc  = (const float*)d_in[10];
  float* out = (float*)d_out;

  char* ws = (char*)d_ws;
  float*    hsum = (float*)(ws + WS_HSUM);
  float*    uv_g = (float*)(ws + WS_UV);
  ushort_t* w_sw = (ushort_t*)(ws + WS_WSW);

  hipFuncSetAttribute((const void*)lstm_main,
                      hipFuncAttributeMaxDynamicSharedMemorySize, DYN_LDS);

  hipMemsetAsync(hsum, 0, (size_t)T_STEPS * 400 * sizeof(float), stream);
  prep_uv<<<2, 256, 0, stream>>>(Wih_f, b_f, Wih_b, b_b, W_in, b_in, uv_g);
  prep_w<<<2 * NMT * NKT, 64, 0, stream>>>(Whh_f, Whh_b, uv_g, w_sw);
  lstm_main<<<64, THREADS, DYN_LDS, stream>>>(x, w_sw, hsum);
  out_proj<<<T_STEPS, 256, 0, stream>>>(hsum, W_fc, b_fc, out);
}

// Round 11
// 1818.224 us; speedup vs baseline: 12.3687x; 1.0094x over previous
//
#include <hip/hip_runtime.h>

// ---------------------------------------------------------------------------
// BiLSTM (T=784, B=512, H=200, D=1) on MI355X — round 11.
//
// Round-10 lesson: weights fully CU-resident (AGPR pins verified: absmax
// exact, arch VGPR 96) yet time UNCHANGED vs streaming rounds => streaming
// was never the floor. The floor shared by rounds 2-10: hsum atomic drain.
// Compiler emits s_waitcnt vmcnt(0) before s_barrier, so each step's 26
// deferred atomics/wave must COMPLETE before the barrier; 32 same-dir blocks
// hammer the same 25 lines per t => ~512 serialized far-point RMWs/line/step
// ~= 3000+ cy drain (WRITE_SIZE 78MB = 10M atomics x 8B confirms the bounce).
// Fix (single variable vs r10): spread hsum into 8 slice-buckets
// hsum8[(t*400+col)*8 + (slice&7)] -> 32 RMWs/line/step, drain hidden under
// compute. out_proj sums the 8 buckets. Atomic count unchanged.
//
// Structure (r10): 64 blocks (dir, 16-batch slice), 512 thr, 8 waves.
// Wave w: 4 weight tiles in fixed AGPRs a0..a111 (inline-asm pin + MFMA,
// clobber-declared; NO other AGPR consumers in the loop) + 2-3 tiles in LDS
// (all-VGPR inline-asm MFMA). h in LDS B-frag order, dbuf; input path folded
// into K-pad slots 200..204; gate-interleaved M.
// ---------------------------------------------------------------------------

typedef short short8 __attribute__((ext_vector_type(8)));
typedef float f32x4 __attribute__((ext_vector_type(4)));
typedef unsigned short ushort_t;

#define T_STEPS 784
#define BATCH   512
#define HID     200
#define NKT     7
#define NMT     50
#define THREADS 512
#define HBUF    3584
#define NLDST   18
#define DYN_LDS (2 * HBUF * 2 + NLDST * NKT * 512 * 2)  // 143360 B

// ws layout (bytes)
#define HS8_FLOATS (T_STEPS * 400 * 8)            // 2,508,800 floats
#define WS_HSUM 0                                  // 10,035,200 B
#define WS_UV   (HS8_FLOATS * 4)                   // 12,800 B
#define WS_WSW  (HS8_FLOATS * 4 + 12800)           // 716,800 B

__device__ __forceinline__ ushort_t f2bf(float f) {
  union { float f; unsigned u; } x; x.f = f;
  return (ushort_t)((x.u + 0x7FFFu + ((x.u >> 16) & 1u)) >> 16);  // RNE
}
__device__ __forceinline__ float bf2f(ushort_t u) {
  union { unsigned u; float f; } x; x.u = (unsigned)u << 16; return x.f;
}

__device__ __forceinline__ float row16_sum(float v) {
  union { float f; int i; } a, b;
  a.f = v;
  b.i = __builtin_amdgcn_update_dpp(0, a.i, 0x118, 0xF, 0xF, true); a.f += b.f;
  b.i = __builtin_amdgcn_update_dpp(0, a.i, 0x114, 0xF, 0xF, true); a.f += b.f;
  b.i = __builtin_amdgcn_update_dpp(0, a.i, 0x112, 0xF, 0xF, true); a.f += b.f;
  b.i = __builtin_amdgcn_update_dpp(0, a.i, 0x111, 0xF, 0xF, true); a.f += b.f;
  return a.f;  // row sum valid at bcol==15
}

// --- AGPR pin: one 4-dword fragment of tile T, k-tile K into fixed a-regs
#define PIN1(T, K, N0, N1, N2, N3)                                            \
  {                                                                           \
    union { short8 s; unsigned u[4]; } cv;                                    \
    cv.s = *(const short8*)(wg +                                              \
        ((size_t)((rbase + (T)) * NKT + (K))) * 512 + lane * 8);              \
    asm volatile("v_accvgpr_write_b32 a" #N0 ", %0\n\t"                       \
                 "v_accvgpr_write_b32 a" #N1 ", %1\n\t"                       \
                 "v_accvgpr_write_b32 a" #N2 ", %2\n\t"                       \
                 "v_accvgpr_write_b32 a" #N3 ", %3"                           \
                 :: "v"(cv.u[0]), "v"(cv.u[1]), "v"(cv.u[2]), "v"(cv.u[3])    \
                 : "a" #N0, "a" #N1, "a" #N2, "a" #N3);                       \
  }

// --- inline-asm MFMA, A from fixed AGPRs
#define MF(N0, N1, N2, N3, ACC, B)                                            \
  asm volatile("v_mfma_f32_16x16x32_bf16 %0, a[" #N0 ":" #N3 "], %1, %0"      \
               : "+v"(ACC) : "v"(B)                                           \
               : "a" #N0, "a" #N1, "a" #N2, "a" #N3)
#define MFS(N0, N1, N2, N3, ACC, B)                                           \
  asm volatile("s_nop 1\n\t"                                                  \
               "v_mfma_f32_16x16x32_bf16 %0, a[" #N0 ":" #N3 "], %1, %0"      \
               : "+v"(ACC) : "v"(B)                                           \
               : "a" #N0, "a" #N1, "a" #N2, "a" #N3)
#define MFE(N0, N1, N2, N3, ACC, B)                                           \
  asm volatile("v_mfma_f32_16x16x32_bf16 %0, a[" #N0 ":" #N3 "], %1, %0\n\t"  \
               "s_nop 7\n\ts_nop 7"                                           \
               : "+v"(ACC) : "v"(B)                                           \
               : "a" #N0, "a" #N1, "a" #N2, "a" #N3)

// --- inline-asm MFMA, all-VGPR (LDS-resident tiles) — keeps AGPRs untouched
#define MFV(ACC, A, B)                                                        \
  asm volatile("v_mfma_f32_16x16x32_bf16 %0, %1, %2, %0"                      \
               : "+v"(ACC) : "v"(A), "v"(B))
#define MFVS(ACC, A, B)                                                       \
  asm volatile("s_nop 1\n\t"                                                  \
               "v_mfma_f32_16x16x32_bf16 %0, %1, %2, %0"                      \
               : "+v"(ACC) : "v"(A), "v"(B))
#define MFVE(ACC, A, B)                                                       \
  asm volatile("v_mfma_f32_16x16x32_bf16 %0, %1, %2, %0\n\t"                  \
               "s_nop 7\n\ts_nop 7"                                           \
               : "+v"(ACC) : "v"(A), "v"(B))

// ---------------------------------------------------------------------------
__global__ void prep_uv(const float* __restrict__ Wih_f, const float* __restrict__ b_f,
                        const float* __restrict__ Wih_b, const float* __restrict__ b_b,
                        const float* __restrict__ W_in, const float* __restrict__ b_in,
                        float* __restrict__ uv_g) {
  const int dir = blockIdx.x, j = threadIdx.x;
  if (j >= HID) return;
  const float* Wih = dir ? Wih_b : Wih_f;
  const float* b   = dir ? b_b   : b_f;
  for (int q = 0; q < 4; ++q) {
    const int row = q * HID + j;
    const float* wr = Wih + (size_t)row * HID;
    float u = 0.f, v = 0.f;
    for (int k = 0; k < HID; ++k) {
      u = fmaf(wr[k], W_in[k], u);
      v = fmaf(wr[k], b_in[k], v);
    }
    uv_g[(size_t)dir * 1600 + j * 8 + q]     = u;
    uv_g[(size_t)dir * 1600 + j * 8 + 4 + q] = v + b[row];
  }
}

// ---------------------------------------------------------------------------
__global__ void prep_w(const float* __restrict__ Whh_f, const float* __restrict__ Whh_b,
                       const float* __restrict__ uv_g, ushort_t* __restrict__ w_sw) {
  const int bid = blockIdx.x, lane = threadIdx.x;
  const int dir = bid / (NMT * NKT);
  const int rem = bid % (NMT * NKT);
  const int mt = rem / NKT, kt = rem % NKT;
  const float* W = dir ? Whh_b : Whh_f;
  const int m = lane & 15;
  const int q = m & 3;
  const int j = mt * 4 + (m >> 2);
  const int row = q * HID + j;
  const int grp = lane >> 4;
  short8 v8 = {0, 0, 0, 0, 0, 0, 0, 0};
  if (kt < 6) {
#pragma unroll
    for (int e = 0; e < 8; ++e)
      v8[e] = (short)f2bf(W[(size_t)row * HID + kt * 32 + grp * 8 + e]);
  } else if (grp == 0) {
#pragma unroll
    for (int e = 0; e < 8; ++e)
      v8[e] = (short)f2bf(W[(size_t)row * HID + 192 + e]);
  } else if (grp == 1) {
    const float U = uv_g[(size_t)dir * 1600 + j * 8 + q];
    const float V = uv_g[(size_t)dir * 1600 + j * 8 + 4 + q];
    const ushort_t vhi = f2bf(V), uhi = f2bf(U);
    v8[0] = (short)vhi;
    v8[1] = (short)f2bf(V - bf2f(vhi));
    v8[2] = (short)uhi;
    v8[3] = (short)f2bf(U - bf2f(uhi));
    v8[4] = (short)uhi;
  }
  *(short8*)(w_sw + (size_t)bid * 512 + (size_t)lane * 8) = v8;
}

// ---------------------------------------------------------------------------
__device__ __forceinline__ void cell_update(const f32x4 a, const int haddr,
                                            ushort_t* __restrict__ hnext,
                                            float& c, float& hold) {
  const float L1 = 1.44269504088896340736f;
  const float ei = __builtin_amdgcn_exp2f(fminf(-L1 * a[0], 30.f));
  const float ef = __builtin_amdgcn_exp2f(fminf(-L1 * a[1], 30.f));
  const float eg = __builtin_amdgcn_exp2f(fminf(-2.f * L1 * a[2], 30.f));
  const float eo = __builtin_amdgcn_exp2f(fminf(-L1 * a[3], 30.f));
  const float pi = 1.f + ei, pf = 1.f + ef, pg = 1.f + eg;
  const float pig = pi * pg;
  const float R1 = __builtin_amdgcn_rcpf(pig * pf);
  const float sf = pig * R1;
  const float sitg = (1.f - eg) * pf * R1;
  const float cn = fmaf(sf, c, sitg);
  c = cn;
  const float ec = __builtin_amdgcn_exp2f(fminf(-2.f * L1 * cn, 83.f));
  const float R2 = __builtin_amdgcn_rcpf((1.f + ec) * (1.f + eo));
  const float h = (1.f - ec) * R2;
  hnext[haddr] = f2bf(h);
  hold = row16_sum(h);
}

// ---------------------------------------------------------------------------
// 784-step scan: 4 AGPR tiles (a0..a111) at rbase.., NLDS LDS tiles at lfirst.
// hsum8 bucket = slice&7 (decontended atomics).
// ---------------------------------------------------------------------------
template <int NLDS>
__device__ __forceinline__ void scan_loop(
    const int rbase, const int lfirst, const int dir, const int b0,
    const int lane, const int wv, const int bkt, const ushort_t* __restrict__ wg,
    const float* __restrict__ x, float* __restrict__ hsum8,
    ushort_t* __restrict__ h_lds, const ushort_t* __restrict__ w_lds_my) {
  constexpr int NREG = 4;
  constexpr int NT = NREG + NLDS;
  const int bcol = lane & 15, krow = lane >> 4;
  const bool xw = (wv == 0) & (krow == 1);

  // pin 4 tiles into fixed AGPRs a0..a111 (28 dwords per tile)
  PIN1(0, 0,  0,  1,  2,  3)  PIN1(0, 1,  4,  5,  6,  7)
  PIN1(0, 2,  8,  9, 10, 11)  PIN1(0, 3, 12, 13, 14, 15)
  PIN1(0, 4, 16, 17, 18, 19)  PIN1(0, 5, 20, 21, 22, 23)
  PIN1(0, 6, 24, 25, 26, 27)
  PIN1(1, 0, 28, 29, 30, 31)  PIN1(1, 1, 32, 33, 34, 35)
  PIN1(1, 2, 36, 37, 38, 39)  PIN1(1, 3, 40, 41, 42, 43)
  PIN1(1, 4, 44, 45, 46, 47)  PIN1(1, 5, 48, 49, 50, 51)
  PIN1(1, 6, 52, 53, 54, 55)
  PIN1(2, 0, 56, 57, 58, 59)  PIN1(2, 1, 60, 61, 62, 63)
  PIN1(2, 2, 64, 65, 66, 67)  PIN1(2, 3, 68, 69, 70, 71)
  PIN1(2, 4, 72, 73, 74, 75)  PIN1(2, 5, 76, 77, 78, 79)
  PIN1(2, 6, 80, 81, 82, 83)
  PIN1(3, 0, 84, 85, 86, 87)  PIN1(3, 1, 88, 89, 90, 91)
  PIN1(3, 2, 92, 93, 94, 95)  PIN1(3, 3, 96, 97, 98, 99)
  PIN1(3, 4, 100, 101, 102, 103)  PIN1(3, 5, 104, 105, 106, 107)
  PIN1(3, 6, 108, 109, 110, 111)
  asm volatile("s_nop 7\n\ts_nop 7");  // accvgpr_write -> mfma-read spacing

  int haddr[NT];
#pragma unroll
  for (int i = 0; i < NT; ++i) {
    const int tile = (i < NREG) ? rbase + i : lfirst + (i - NREG);
    const int j = tile * 4 + krow;
    haddr[i] = (j >> 5) * 512 + (bcol | (((j >> 3) & 3) << 4)) * 8 + (j & 7);
  }
  float c[NT], hold[NT];
#pragma unroll
  for (int i = 0; i < NT; ++i) { c[i] = 0.f; hold[i] = 0.f; }

  const int dcol = dir * HID;
  const int jb = rbase * 4 + krow;
  const int jl = lfirst * 4 + krow;
  int t_prev = 0, cur = 0;

  for (int s = 0; s < T_STEPS; ++s) {
    const int t = dir ? (T_STEPS - 1 - s) : s;

    if (s > 0 && bcol == 15) {
#pragma unroll
      for (int i = 0; i < NREG; ++i)
        atomicAdd(&hsum8[((size_t)t_prev * 400 + dcol + jb + 4 * i) * 8 + bkt],
                  hold[i]);
#pragma unroll
      for (int i = 0; i < NLDS; ++i)
        atomicAdd(&hsum8[((size_t)t_prev * 400 + dcol + jl + 4 * i) * 8 + bkt],
                  hold[NREG + i]);
    }

    const int sn = (s + 1 < T_STEPS) ? s + 1 : s;
    float xn = 0.f;
    if (xw) xn = x[(size_t)(dir ? T_STEPS - 1 - sn : sn) * BATCH + b0 + bcol];

    short8 bf[NKT];
#pragma unroll
    for (int kt = 0; kt < NKT; ++kt)
      bf[kt] = *(const short8*)&h_lds[cur * HBUF + kt * 512 + lane * 8];

    ushort_t* hnext = h_lds + (cur ^ 1) * HBUF;

    if (xw) {
      const ushort_t hi = f2bf(xn);
      const ushort_t lo = f2bf(xn - bf2f(hi));
      const int sb = 6 * 512 + lane * 8;
      hnext[sb + 2] = hi;
      hnext[sb + 3] = hi;
      hnext[sb + 4] = lo;
    }

    // AGPR tiles 0,1 (two independent chains)
    {
      f32x4 a0 = {0.f, 0.f, 0.f, 0.f}, a1 = {0.f, 0.f, 0.f, 0.f};
      MFS(0, 1, 2, 3, a0, bf[0]);      MFS(28, 29, 30, 31, a1, bf[0]);
      MF(4, 5, 6, 7, a0, bf[1]);       MF(32, 33, 34, 35, a1, bf[1]);
      MF(8, 9, 10, 11, a0, bf[2]);     MF(36, 37, 38, 39, a1, bf[2]);
      MF(12, 13, 14, 15, a0, bf[3]);   MF(40, 41, 42, 43, a1, bf[3]);
      MF(16, 17, 18, 19, a0, bf[4]);   MF(44, 45, 46, 47, a1, bf[4]);
      MF(20, 21, 22, 23, a0, bf[5]);   MF(48, 49, 50, 51, a1, bf[5]);
      MFE(24, 25, 26, 27, a0, bf[6]);  MFE(52, 53, 54, 55, a1, bf[6]);
      cell_update(a0, haddr[0], hnext, c[0], hold[0]);
      cell_update(a1, haddr[1], hnext, c[1], hold[1]);
    }
    // AGPR tiles 2,3
    {
      f32x4 a0 = {0.f, 0.f, 0.f, 0.f}, a1 = {0.f, 0.f, 0.f, 0.f};
      MFS(56, 57, 58, 59, a0, bf[0]);  MFS(84, 85, 86, 87, a1, bf[0]);
      MF(60, 61, 62, 63, a0, bf[1]);   MF(88, 89, 90, 91, a1, bf[1]);
      MF(64, 65, 66, 67, a0, bf[2]);   MF(92, 93, 94, 95, a1, bf[2]);
      MF(68, 69, 70, 71, a0, bf[3]);   MF(96, 97, 98, 99, a1, bf[3]);
      MF(72, 73, 74, 75, a0, bf[4]);   MF(100, 101, 102, 103, a1, bf[4]);
      MF(76, 77, 78, 79, a0, bf[5]);   MF(104, 105, 106, 107, a1, bf[5]);
      MFE(80, 81, 82, 83, a0, bf[6]);  MFE(108, 109, 110, 111, a1, bf[6]);
      cell_update(a0, haddr[2], hnext, c[2], hold[2]);
      cell_update(a1, haddr[3], hnext, c[3], hold[3]);
    }
    // LDS tiles — inline-asm all-VGPR MFMA (no AGPR use anywhere here)
#pragma unroll
    for (int p = 0; p + 1 < NLDS; p += 2) {
      const int i0 = NREG + p, i1 = NREG + p + 1;
      f32x4 a0 = {0.f, 0.f, 0.f, 0.f}, a1 = {0.f, 0.f, 0.f, 0.f};
      {
        const short8 af0 = *(const short8*)&w_lds_my[((p)     * NKT + 0) * 512 + lane * 8];
        const short8 af1 = *(const short8*)&w_lds_my[((p + 1) * NKT + 0) * 512 + lane * 8];
        MFVS(a0, af0, bf[0]);  MFVS(a1, af1, bf[0]);
      }
#pragma unroll
      for (int kt = 1; kt < NKT - 1; ++kt) {
        const short8 af0 = *(const short8*)&w_lds_my[((p)     * NKT + kt) * 512 + lane * 8];
        const short8 af1 = *(const short8*)&w_lds_my[((p + 1) * NKT + kt) * 512 + lane * 8];
        MFV(a0, af0, bf[kt]);  MFV(a1, af1, bf[kt]);
      }
      {
        const short8 af0 = *(const short8*)&w_lds_my[((p)     * NKT + 6) * 512 + lane * 8];
        const short8 af1 = *(const short8*)&w_lds_my[((p + 1) * NKT + 6) * 512 + lane * 8];
        MFVE(a0, af0, bf[6]);  MFVE(a1, af1, bf[6]);
      }
      cell_update(a0, haddr[i0], hnext, c[i0], hold[i0]);
      cell_update(a1, haddr[i1], hnext, c[i1], hold[i1]);
    }
    if constexpr (NLDS & 1) {
      constexpr int p = NLDS - 1;
      const int i0 = NREG + p;
      f32x4 a0 = {0.f, 0.f, 0.f, 0.f};
      {
        const short8 af = *(const short8*)&w_lds_my[(p * NKT + 0) * 512 + lane * 8];
        MFVS(a0, af, bf[0]);
      }
#pragma unroll
      for (int kt = 1; kt < NKT - 1; ++kt) {
        const short8 af = *(const short8*)&w_lds_my[(p * NKT + kt) * 512 + lane * 8];
        MFV(a0, af, bf[kt]);
      }
      {
        const short8 af = *(const short8*)&w_lds_my[(p * NKT + 6) * 512 + lane * 8];
        MFVE(a0, af, bf[6]);
      }
      cell_update(a0, haddr[i0], hnext, c[i0], hold[i0]);
    }

    t_prev = t;
    __syncthreads();
    cur ^= 1;
  }
  if (bcol == 15) {
#pragma unroll
    for (int i = 0; i < NREG; ++i)
      atomicAdd(&hsum8[((size_t)t_prev * 400 + dcol + jb + 4 * i) * 8 + bkt],
                hold[i]);
#pragma unroll
    for (int i = 0; i < NLDS; ++i)
      atomicAdd(&hsum8[((size_t)t_prev * 400 + dcol + jl + 4 * i) * 8 + bkt],
                hold[NREG + i]);
  }
}

// ---------------------------------------------------------------------------
// main scan kernel: 64 blocks, 512 threads, 2 waves/SIMD (112 AGPR + ~96 VGPR)
// ---------------------------------------------------------------------------
__global__ __launch_bounds__(THREADS, 2) void lstm_main(
    const float* __restrict__ x, const ushort_t* __restrict__ w_sw,
    float* __restrict__ hsum8) {
  extern __shared__ __align__(16) ushort_t dynlds[];
  ushort_t* h_lds = dynlds;
  ushort_t* w_lds = dynlds + 2 * HBUF;

  const int tid = threadIdx.x;
  const int lane = tid & 63;
  const int wv = tid >> 6;
  const int dir = blockIdx.x & 1;
  const int slice = blockIdx.x >> 1;
  const int b0 = slice * 16;
  const int bkt = slice & 7;

  const ushort_t* wg = w_sw + (size_t)dir * NMT * NKT * 512;

  for (int i = tid; i < HBUF; i += THREADS) ((unsigned*)h_lds)[i] = 0;
  for (int i = tid; i < NLDST * NKT * 64; i += THREADS)
    *(short8*)&w_lds[(size_t)i * 8] =
        *(const short8*)(wg + (size_t)32 * NKT * 512 + (size_t)i * 8);
  __syncthreads();

  if (tid < 16) {
    const int t0 = dir ? T_STEPS - 1 : 0;
    const float x0 = x[(size_t)t0 * BATCH + b0 + tid];
    const ushort_t hi = f2bf(x0);
    const ushort_t lo = f2bf(x0 - bf2f(hi));
    const int sb = 6 * 512 + (16 + tid) * 8;
    h_lds[sb + 0] = 0x3F80; h_lds[sb + 1] = 0x3F80;
    h_lds[HBUF + sb + 0] = 0x3F80; h_lds[HBUF + sb + 1] = 0x3F80;
    h_lds[sb + 2] = hi; h_lds[sb + 3] = hi; h_lds[sb + 4] = lo;
  }
  __syncthreads();

  const int rbase = 4 * wv;
  const int lfirst = (wv < 6) ? (32 + 2 * wv) : (44 + 3 * (wv - 6));
  const ushort_t* wl = w_lds + (size_t)(lfirst - 32) * NKT * 512;
  if (wv < 6)
    scan_loop<2>(rbase, lfirst, dir, b0, lane, wv, bkt, wg, x, hsum8, h_lds, wl);
  else
    scan_loop<3>(rbase, lfirst, dir, b0, lane, wv, bkt, wg, x, hsum8, h_lds, wl);
}

// ---------------------------------------------------------------------------
// out[t][o] = b_fc[o] + (1/512) * sum_col (sum_b hsum8[t][col][b]) * W_fc[o][col]
// ---------------------------------------------------------------------------
__global__ void out_proj(const float* __restrict__ hsum8, const float* __restrict__ Wfc,
                         const float* __restrict__ bfc, float* __restrict__ out) {
  const int t = blockIdx.x, tid = threadIdx.x;
  float a[10] = {0.f, 0.f, 0.f, 0.f, 0.f, 0.f, 0.f, 0.f, 0.f, 0.f};
  for (int col = tid; col < 400; col += 256) {
    const float* hb = hsum8 + ((size_t)t * 400 + col) * 8;
    float s = 0.f;
#pragma unroll
    for (int b = 0; b < 8; ++b) s += hb[b];
    const float hv = s * (1.f / 512.f);
#pragma unroll
    for (int o = 0; o < 10; ++o) a[o] = fmaf(hv, Wfc[o * 400 + col], a[o]);
  }
#pragma unroll
  for (int o = 0; o < 10; ++o) {
    float v = a[o];
    for (int m = 32; m; m >>= 1) v += __shfl_xor(v, m);
    a[o] = v;
  }
  __shared__ float red[4][10];
  if ((tid & 63) == 0)
#pragma unroll
    for (int o = 0; o < 10; ++o) red[tid >> 6][o] = a[o];
  __syncthreads();
  if (tid < 10)
    out[t * 10 + tid] = bfc[tid] + red[0][tid] + red[1][tid] + red[2][tid] + red[3][tid];
}

extern "C" void kernel_launch(void* const* d_in, const int* in_sizes, int n_in,
                              void* d_out, int out_size, void* d_ws, size_t ws_size,
                              hipStream_t stream) {
  const float* x     = (const float*)d_in[0];
  const float* W_in  = (const float*)d_in[1];
  const float* b_in  = (const float*)d_in[2];
  const float* Wih_f = (const float*)d_in[3];
  const float* Whh_f = (const float*)d_in[4];
  const float* b_f   = (const float*)d_in[5];
  const float* Wih_b = (const float*)d_in[6];
  const float* Whh_b = (const float*)d_in[7];
  const float* b_b   = (const float*)d_in[8];
  const float* W_fc  = (const float*)d_in[9];
  const float* b_fc  = (const float*)d_in[10];
  float* out = (float*)d_out;

  char* ws = (char*)d_ws;
  float*    hsum8 = (float*)(ws + WS_HSUM);
  float*    uv_g  = (float*)(ws + WS_UV);
  ushort_t* w_sw  = (ushort_t*)(ws + WS_WSW);

  hipFuncSetAttribute((const void*)lstm_main,
                      hipFuncAttributeMaxDynamicSharedMemorySize, DYN_LDS);

  hipMemsetAsync(hsum8, 0, (size_t)HS8_FLOATS * sizeof(float), stream);
  prep_uv<<<2, 256, 0, stream>>>(Wih_f, b_f, Wih_b, b_b, W_in, b_in, uv_g);
  prep_w<<<2 * NMT * NKT, 64, 0, stream>>>(Whh_f, Whh_b, uv_g, w_sw);
  lstm_main<<<64, THREADS, DYN_LDS, stream>>>(x, w_sw, hsum8);
  out_proj<<<T_STEPS, 256, 0, stream>>>(hsum8, W_fc, b_fc, out);
}

// Round 12
// 1806.090 us; speedup vs baseline: 12.4518x; 1.0067x over previous
//
#include <hip/hip_runtime.h>

// ---------------------------------------------------------------------------
// BiLSTM (T=784, B=512, H=200, D=1) on MI355X — round 12.
//
// Round-11 lesson: atomic decontention = no change; scaling counters to the
// 64 ACTIVE CUs gives VALUBusy~48%, MfmaUtil~25% -> VALU issue is the top
// consumer, and measured ~670 VALU/wave/step vs ~250 algorithmic. The gap is
// self-inflicted: per-asm-statement register shuffles + 24 acc-zero movs per
// step + 26 x 64-bit atomic address recomputes. Round 12 strips it:
//  1) AGPR region = ONE asm block (28 MFMAs, 4 chains interleaved by kt,
//     ILP-4); C of kt=0 is a persistent pinned zero4 reg -> no per-step init.
//  2) LDS tiles: per-kt fused 2-MFMA asm, zero4 for kt=0, nops folded into
//     the kt=6 variant (hazard nops can't be bypassed by hoisted VALU).
//  3) atomics: uniform per-step base (SALU) + precomputed voffsets.
// Structure otherwise identical to r11 (64 blocks, 512 thr, AGPR pins
// a0..a111 + 18 LDS tiles, h dbuf in LDS, input path in K-pad slots,
// hsum8 slice-buckets).
// ---------------------------------------------------------------------------

typedef short short8 __attribute__((ext_vector_type(8)));
typedef float f32x4 __attribute__((ext_vector_type(4)));
typedef unsigned short ushort_t;

#define T_STEPS 784
#define BATCH   512
#define HID     200
#define NKT     7
#define NMT     50
#define THREADS 512
#define HBUF    3584
#define NLDST   18
#define DYN_LDS (2 * HBUF * 2 + NLDST * NKT * 512 * 2)  // 143360 B

// ws layout (bytes)
#define HS8_FLOATS (T_STEPS * 400 * 8)
#define WS_HSUM 0
#define WS_UV   (HS8_FLOATS * 4)
#define WS_WSW  (HS8_FLOATS * 4 + 12800)

#define ACLOB \
  "a0","a1","a2","a3","a4","a5","a6","a7","a8","a9","a10","a11","a12","a13", \
  "a14","a15","a16","a17","a18","a19","a20","a21","a22","a23","a24","a25",   \
  "a26","a27","a28","a29","a30","a31","a32","a33","a34","a35","a36","a37",   \
  "a38","a39","a40","a41","a42","a43","a44","a45","a46","a47","a48","a49",   \
  "a50","a51","a52","a53","a54","a55","a56","a57","a58","a59","a60","a61",   \
  "a62","a63","a64","a65","a66","a67","a68","a69","a70","a71","a72","a73",   \
  "a74","a75","a76","a77","a78","a79","a80","a81","a82","a83","a84","a85",   \
  "a86","a87","a88","a89","a90","a91","a92","a93","a94","a95","a96","a97",   \
  "a98","a99","a100","a101","a102","a103","a104","a105","a106","a107",       \
  "a108","a109","a110","a111"

__device__ __forceinline__ ushort_t f2bf(float f) {
  union { float f; unsigned u; } x; x.f = f;
  return (ushort_t)((x.u + 0x7FFFu + ((x.u >> 16) & 1u)) >> 16);  // RNE
}
__device__ __forceinline__ float bf2f(ushort_t u) {
  union { unsigned u; float f; } x; x.u = (unsigned)u << 16; return x.f;
}

__device__ __forceinline__ float row16_sum(float v) {
  union { float f; int i; } a, b;
  a.f = v;
  b.i = __builtin_amdgcn_update_dpp(0, a.i, 0x118, 0xF, 0xF, true); a.f += b.f;
  b.i = __builtin_amdgcn_update_dpp(0, a.i, 0x114, 0xF, 0xF, true); a.f += b.f;
  b.i = __builtin_amdgcn_update_dpp(0, a.i, 0x112, 0xF, 0xF, true); a.f += b.f;
  b.i = __builtin_amdgcn_update_dpp(0, a.i, 0x111, 0xF, 0xF, true); a.f += b.f;
  return a.f;  // row sum valid at bcol==15
}

// --- AGPR pin: one 4-dword fragment of tile T, k-tile K into fixed a-regs
#define PIN1(T, K, N0, N1, N2, N3)                                            \
  {                                                                           \
    union { short8 s; unsigned u[4]; } cv;                                    \
    cv.s = *(const short8*)(wg +                                              \
        ((size_t)((rbase + (T)) * NKT + (K))) * 512 + lane * 8);              \
    asm volatile("v_accvgpr_write_b32 a" #N0 ", %0\n\t"                       \
                 "v_accvgpr_write_b32 a" #N1 ", %1\n\t"                       \
                 "v_accvgpr_write_b32 a" #N2 ", %2\n\t"                       \
                 "v_accvgpr_write_b32 a" #N3 ", %3"                           \
                 :: "v"(cv.u[0]), "v"(cv.u[1]), "v"(cv.u[2]), "v"(cv.u[3])    \
                 : "a" #N0, "a" #N1, "a" #N2, "a" #N3);                       \
  }

// ---------------------------------------------------------------------------
__global__ void prep_uv(const float* __restrict__ Wih_f, const float* __restrict__ b_f,
                        const float* __restrict__ Wih_b, const float* __restrict__ b_b,
                        const float* __restrict__ W_in, const float* __restrict__ b_in,
                        float* __restrict__ uv_g) {
  const int dir = blockIdx.x, j = threadIdx.x;
  if (j >= HID) return;
  const float* Wih = dir ? Wih_b : Wih_f;
  const float* b   = dir ? b_b   : b_f;
  for (int q = 0; q < 4; ++q) {
    const int row = q * HID + j;
    const float* wr = Wih + (size_t)row * HID;
    float u = 0.f, v = 0.f;
    for (int k = 0; k < HID; ++k) {
      u = fmaf(wr[k], W_in[k], u);
      v = fmaf(wr[k], b_in[k], v);
    }
    uv_g[(size_t)dir * 1600 + j * 8 + q]     = u;
    uv_g[(size_t)dir * 1600 + j * 8 + 4 + q] = v + b[row];
  }
}

// ---------------------------------------------------------------------------
__global__ void prep_w(const float* __restrict__ Whh_f, const float* __restrict__ Whh_b,
                       const float* __restrict__ uv_g, ushort_t* __restrict__ w_sw) {
  const int bid = blockIdx.x, lane = threadIdx.x;
  const int dir = bid / (NMT * NKT);
  const int rem = bid % (NMT * NKT);
  const int mt = rem / NKT, kt = rem % NKT;
  const float* W = dir ? Whh_b : Whh_f;
  const int m = lane & 15;
  const int q = m & 3;
  const int j = mt * 4 + (m >> 2);
  const int row = q * HID + j;
  const int grp = lane >> 4;
  short8 v8 = {0, 0, 0, 0, 0, 0, 0, 0};
  if (kt < 6) {
#pragma unroll
    for (int e = 0; e < 8; ++e)
      v8[e] = (short)f2bf(W[(size_t)row * HID + kt * 32 + grp * 8 + e]);
  } else if (grp == 0) {
#pragma unroll
    for (int e = 0; e < 8; ++e)
      v8[e] = (short)f2bf(W[(size_t)row * HID + 192 + e]);
  } else if (grp == 1) {
    const float U = uv_g[(size_t)dir * 1600 + j * 8 + q];
    const float V = uv_g[(size_t)dir * 1600 + j * 8 + 4 + q];
    const ushort_t vhi = f2bf(V), uhi = f2bf(U);
    v8[0] = (short)vhi;
    v8[1] = (short)f2bf(V - bf2f(vhi));
    v8[2] = (short)uhi;
    v8[3] = (short)f2bf(U - bf2f(uhi));
    v8[4] = (short)uhi;
  }
  *(short8*)(w_sw + (size_t)bid * 512 + (size_t)lane * 8) = v8;
}

// ---------------------------------------------------------------------------
__device__ __forceinline__ void cell_update(const f32x4 a, const int haddr,
                                            ushort_t* __restrict__ hnext,
                                            float& c, float& hold) {
  const float L1 = 1.44269504088896340736f;
  const float ei = __builtin_amdgcn_exp2f(fminf(-L1 * a[0], 30.f));
  const float ef = __builtin_amdgcn_exp2f(fminf(-L1 * a[1], 30.f));
  const float eg = __builtin_amdgcn_exp2f(fminf(-2.f * L1 * a[2], 30.f));
  const float eo = __builtin_amdgcn_exp2f(fminf(-L1 * a[3], 30.f));
  const float pi = 1.f + ei, pf = 1.f + ef, pg = 1.f + eg;
  const float pig = pi * pg;
  const float R1 = __builtin_amdgcn_rcpf(pig * pf);
  const float sf = pig * R1;
  const float sitg = (1.f - eg) * pf * R1;
  const float cn = fmaf(sf, c, sitg);
  c = cn;
  const float ec = __builtin_amdgcn_exp2f(fminf(-2.f * L1 * cn, 83.f));
  const float R2 = __builtin_amdgcn_rcpf((1.f + ec) * (1.f + eo));
  const float h = (1.f - ec) * R2;
  hnext[haddr] = f2bf(h);
  hold = row16_sum(h);
}

// ---------------------------------------------------------------------------
// 784-step scan: 4 AGPR tiles (a0..a111) at rbase.., NLDS LDS tiles at lfirst.
// ---------------------------------------------------------------------------
template <int NLDS>
__device__ __forceinline__ void scan_loop(
    const int rbase, const int lfirst, const int dir, const int b0,
    const int lane, const int wv, const int bkt, const ushort_t* __restrict__ wg,
    const float* __restrict__ x, float* __restrict__ hsum8,
    ushort_t* __restrict__ h_lds, const ushort_t* __restrict__ w_lds_my) {
  constexpr int NREG = 4;
  constexpr int NT = NREG + NLDS;
  const int bcol = lane & 15, krow = lane >> 4;
  const bool xw = (wv == 0) & (krow == 1);

  // pin 4 tiles into fixed AGPRs a0..a111 (28 dwords per tile)
  PIN1(0, 0,  0,  1,  2,  3)  PIN1(0, 1,  4,  5,  6,  7)
  PIN1(0, 2,  8,  9, 10, 11)  PIN1(0, 3, 12, 13, 14, 15)
  PIN1(0, 4, 16, 17, 18, 19)  PIN1(0, 5, 20, 21, 22, 23)
  PIN1(0, 6, 24, 25, 26, 27)
  PIN1(1, 0, 28, 29, 30, 31)  PIN1(1, 1, 32, 33, 34, 35)
  PIN1(1, 2, 36, 37, 38, 39)  PIN1(1, 3, 40, 41, 42, 43)
  PIN1(1, 4, 44, 45, 46, 47)  PIN1(1, 5, 48, 49, 50, 51)
  PIN1(1, 6, 52, 53, 54, 55)
  PIN1(2, 0, 56, 57, 58, 59)  PIN1(2, 1, 60, 61, 62, 63)
  PIN1(2, 2, 64, 65, 66, 67)  PIN1(2, 3, 68, 69, 70, 71)
  PIN1(2, 4, 72, 73, 74, 75)  PIN1(2, 5, 76, 77, 78, 79)
  PIN1(2, 6, 80, 81, 82, 83)
  PIN1(3, 0, 84, 85, 86, 87)  PIN1(3, 1, 88, 89, 90, 91)
  PIN1(3, 2, 92, 93, 94, 95)  PIN1(3, 3, 96, 97, 98, 99)
  PIN1(3, 4, 100, 101, 102, 103)  PIN1(3, 5, 104, 105, 106, 107)
  PIN1(3, 6, 108, 109, 110, 111)
  asm volatile("s_nop 7\n\ts_nop 7");  // accvgpr_write -> mfma-read spacing

  // persistent zero quad (C operand for every chain's first MFMA)
  f32x4 zero4 = {0.f, 0.f, 0.f, 0.f};
  asm volatile("" : "+v"(zero4));

  int haddr[NT], aoff[NT];
  const int dcol = dir * HID;
#pragma unroll
  for (int i = 0; i < NT; ++i) {
    const int tile = (i < NREG) ? rbase + i : lfirst + (i - NREG);
    const int j = tile * 4 + krow;
    haddr[i] = (j >> 5) * 512 + (bcol | (((j >> 3) & 3) << 4)) * 8 + (j & 7);
    aoff[i] = (dcol + j) * 8 + bkt;   // loop-invariant atomic voffset
  }
  float c[NT], hold[NT];
#pragma unroll
  for (int i = 0; i < NT; ++i) { c[i] = 0.f; hold[i] = 0.f; }

  int t_prev = 0, cur = 0;

  for (int s = 0; s < T_STEPS; ++s) {
    const int t = dir ? (T_STEPS - 1 - s) : s;

    // B-fragments of [h(t-1); 1; x(t)] — issue loads first
    short8 bf[NKT];
#pragma unroll
    for (int kt = 0; kt < NKT; ++kt)
      bf[kt] = *(const short8*)&h_lds[cur * HBUF + kt * 512 + lane * 8];

    const int sn = (s + 1 < T_STEPS) ? s + 1 : s;
    float xn = 0.f;
    if (xw) xn = x[(size_t)(dir ? T_STEPS - 1 - sn : sn) * BATCH + b0 + bcol];

    // deferred hsum atomics: uniform base (SALU) + precomputed voffset
    if (s > 0 && bcol == 15) {
      float* hb = hsum8 + (size_t)t_prev * 3200;
#pragma unroll
      for (int i = 0; i < NT; ++i) atomicAdd(hb + aoff[i], hold[i]);
    }

    ushort_t* hnext = h_lds + (cur ^ 1) * HBUF;

    if (xw) {
      const ushort_t hi = f2bf(xn);
      const ushort_t lo = f2bf(xn - bf2f(hi));
      const int sb = 6 * 512 + lane * 8;
      hnext[sb + 2] = hi;
      hnext[sb + 3] = hi;
      hnext[sb + 4] = lo;
    }

    // ---- AGPR region: ONE asm block, 28 MFMAs, 4 chains interleaved ----
    f32x4 a0, a1, a2, a3;
    asm volatile(
      "s_nop 1\n\t"
      "v_mfma_f32_16x16x32_bf16 %0, a[0:3],    %4, %11\n\t"
      "v_mfma_f32_16x16x32_bf16 %1, a[28:31],  %4, %11\n\t"
      "v_mfma_f32_16x16x32_bf16 %2, a[56:59],  %4, %11\n\t"
      "v_mfma_f32_16x16x32_bf16 %3, a[84:87],  %4, %11\n\t"
      "v_mfma_f32_16x16x32_bf16 %0, a[4:7],    %5, %0\n\t"
      "v_mfma_f32_16x16x32_bf16 %1, a[32:35],  %5, %1\n\t"
      "v_mfma_f32_16x16x32_bf16 %2, a[60:63],  %5, %2\n\t"
      "v_mfma_f32_16x16x32_bf16 %3, a[88:91],  %5, %3\n\t"
      "v_mfma_f32_16x16x32_bf16 %0, a[8:11],   %6, %0\n\t"
      "v_mfma_f32_16x16x32_bf16 %1, a[36:39],  %6, %1\n\t"
      "v_mfma_f32_16x16x32_bf16 %2, a[64:67],  %6, %2\n\t"
      "v_mfma_f32_16x16x32_bf16 %3, a[92:95],  %6, %3\n\t"
      "v_mfma_f32_16x16x32_bf16 %0, a[12:15],  %7, %0\n\t"
      "v_mfma_f32_16x16x32_bf16 %1, a[40:43],  %7, %1\n\t"
      "v_mfma_f32_16x16x32_bf16 %2, a[68:71],  %7, %2\n\t"
      "v_mfma_f32_16x16x32_bf16 %3, a[96:99],  %7, %3\n\t"
      "v_mfma_f32_16x16x32_bf16 %0, a[16:19],  %8, %0\n\t"
      "v_mfma_f32_16x16x32_bf16 %1, a[44:47],  %8, %1\n\t"
      "v_mfma_f32_16x16x32_bf16 %2, a[72:75],  %8, %2\n\t"
      "v_mfma_f32_16x16x32_bf16 %3, a[100:103],%8, %3\n\t"
      "v_mfma_f32_16x16x32_bf16 %0, a[20:23],  %9, %0\n\t"
      "v_mfma_f32_16x16x32_bf16 %1, a[48:51],  %9, %1\n\t"
      "v_mfma_f32_16x16x32_bf16 %2, a[76:79],  %9, %2\n\t"
      "v_mfma_f32_16x16x32_bf16 %3, a[104:107],%9, %3\n\t"
      "v_mfma_f32_16x16x32_bf16 %0, a[24:27],  %10, %0\n\t"
      "v_mfma_f32_16x16x32_bf16 %1, a[52:55],  %10, %1\n\t"
      "v_mfma_f32_16x16x32_bf16 %2, a[80:83],  %10, %2\n\t"
      "v_mfma_f32_16x16x32_bf16 %3, a[108:111],%10, %3\n\t"
      "s_nop 7\n\ts_nop 7"
      : "=&v"(a0), "=&v"(a1), "=&v"(a2), "=&v"(a3)
      : "v"(bf[0]), "v"(bf[1]), "v"(bf[2]), "v"(bf[3]), "v"(bf[4]),
        "v"(bf[5]), "v"(bf[6]), "v"(zero4)
      : ACLOB);
    cell_update(a0, haddr[0], hnext, c[0], hold[0]);
    cell_update(a1, haddr[1], hnext, c[1], hold[1]);
    cell_update(a2, haddr[2], hnext, c[2], hold[2]);
    cell_update(a3, haddr[3], hnext, c[3], hold[3]);

    // ---- LDS tiles: per-kt fused 2-MFMA asm, zero4 C at kt=0, nops in kt=6
#pragma unroll
    for (int p = 0; p + 1 < NLDS; p += 2) {
      const int i0 = NREG + p, i1 = NREG + p + 1;
      f32x4 b0r, b1r;
      {
        const short8 af0 = *(const short8*)&w_lds_my[((p)     * NKT + 0) * 512 + lane * 8];
        const short8 af1 = *(const short8*)&w_lds_my[((p + 1) * NKT + 0) * 512 + lane * 8];
        asm volatile("s_nop 1\n\t"
                     "v_mfma_f32_16x16x32_bf16 %0, %2, %4, %5\n\t"
                     "v_mfma_f32_16x16x32_bf16 %1, %3, %4, %5"
                     : "=&v"(b0r), "=&v"(b1r)
                     : "v"(af0), "v"(af1), "v"(bf[0]), "v"(zero4));
      }
#pragma unroll
      for (int kt = 1; kt < NKT - 1; ++kt) {
        const short8 af0 = *(const short8*)&w_lds_my[((p)     * NKT + kt) * 512 + lane * 8];
        const short8 af1 = *(const short8*)&w_lds_my[((p + 1) * NKT + kt) * 512 + lane * 8];
        asm volatile("v_mfma_f32_16x16x32_bf16 %0, %2, %4, %0\n\t"
                     "v_mfma_f32_16x16x32_bf16 %1, %3, %4, %1"
                     : "+v"(b0r), "+v"(b1r)
                     : "v"(af0), "v"(af1), "v"(bf[kt]));
      }
      {
        const short8 af0 = *(const short8*)&w_lds_my[((p)     * NKT + 6) * 512 + lane * 8];
        const short8 af1 = *(const short8*)&w_lds_my[((p + 1) * NKT + 6) * 512 + lane * 8];
        asm volatile("v_mfma_f32_16x16x32_bf16 %0, %2, %4, %0\n\t"
                     "v_mfma_f32_16x16x32_bf16 %1, %3, %4, %1\n\t"
                     "s_nop 7\n\ts_nop 7"
                     : "+v"(b0r), "+v"(b1r)
                     : "v"(af0), "v"(af1), "v"(bf[6]));
      }
      cell_update(b0r, haddr[i0], hnext, c[i0], hold[i0]);
      cell_update(b1r, haddr[i1], hnext, c[i1], hold[i1]);
    }
    if constexpr (NLDS & 1) {
      constexpr int p = NLDS - 1;
      const int i0 = NREG + p;
      f32x4 b0r;
      {
        const short8 af = *(const short8*)&w_lds_my[(p * NKT + 0) * 512 + lane * 8];
        asm volatile("s_nop 1\n\t"
                     "v_mfma_f32_16x16x32_bf16 %0, %1, %2, %3"
                     : "=&v"(b0r) : "v"(af), "v"(bf[0]), "v"(zero4));
      }
#pragma unroll
      for (int kt = 1; kt < NKT - 1; ++kt) {
        const short8 af = *(const short8*)&w_lds_my[(p * NKT + kt) * 512 + lane * 8];
        asm volatile("v_mfma_f32_16x16x32_bf16 %0, %1, %2, %0"
                     : "+v"(b0r) : "v"(af), "v"(bf[kt]));
      }
      {
        const short8 af = *(const short8*)&w_lds_my[(p * NKT + 6) * 512 + lane * 8];
        asm volatile("v_mfma_f32_16x16x32_bf16 %0, %1, %2, %0\n\t"
                     "s_nop 7\n\ts_nop 7"
                     : "+v"(b0r) : "v"(af), "v"(bf[6]));
      }
      cell_update(b0r, haddr[i0], hnext, c[i0], hold[i0]);
    }

    t_prev = t;
    __syncthreads();
    cur ^= 1;
  }
  if (bcol == 15) {
    float* hb = hsum8 + (size_t)t_prev * 3200;
#pragma unroll
    for (int i = 0; i < NT; ++i) atomicAdd(hb + aoff[i], hold[i]);
  }
}

// ---------------------------------------------------------------------------
// main scan kernel: 64 blocks, 512 threads, 2 waves/SIMD (112 AGPR + ~110 VGPR)
// ---------------------------------------------------------------------------
__global__ __launch_bounds__(THREADS, 2) void lstm_main(
    const float* __restrict__ x, const ushort_t* __restrict__ w_sw,
    float* __restrict__ hsum8) {
  extern __shared__ __align__(16) ushort_t dynlds[];
  ushort_t* h_lds = dynlds;
  ushort_t* w_lds = dynlds + 2 * HBUF;

  const int tid = threadIdx.x;
  const int lane = tid & 63;
  const int wv = tid >> 6;
  const int dir = blockIdx.x & 1;
  const int slice = blockIdx.x >> 1;
  const int b0 = slice * 16;
  const int bkt = slice & 7;

  const ushort_t* wg = w_sw + (size_t)dir * NMT * NKT * 512;

  for (int i = tid; i < HBUF; i += THREADS) ((unsigned*)h_lds)[i] = 0;
  for (int i = tid; i < NLDST * NKT * 64; i += THREADS)
    *(short8*)&w_lds[(size_t)i * 8] =
        *(const short8*)(wg + (size_t)32 * NKT * 512 + (size_t)i * 8);
  __syncthreads();

  if (tid < 16) {
    const int t0 = dir ? T_STEPS - 1 : 0;
    const float x0 = x[(size_t)t0 * BATCH + b0 + tid];
    const ushort_t hi = f2bf(x0);
    const ushort_t lo = f2bf(x0 - bf2f(hi));
    const int sb = 6 * 512 + (16 + tid) * 8;
    h_lds[sb + 0] = 0x3F80; h_lds[sb + 1] = 0x3F80;
    h_lds[HBUF + sb + 0] = 0x3F80; h_lds[HBUF + sb + 1] = 0x3F80;
    h_lds[sb + 2] = hi; h_lds[sb + 3] = hi; h_lds[sb + 4] = lo;
  }
  __syncthreads();

  const int rbase = 4 * wv;
  const int lfirst = (wv < 6) ? (32 + 2 * wv) : (44 + 3 * (wv - 6));
  const ushort_t* wl = w_lds + (size_t)(lfirst - 32) * NKT * 512;
  if (wv < 6)
    scan_loop<2>(rbase, lfirst, dir, b0, lane, wv, bkt, wg, x, hsum8, h_lds, wl);
  else
    scan_loop<3>(rbase, lfirst, dir, b0, lane, wv, bkt, wg, x, hsum8, h_lds, wl);
}

// ---------------------------------------------------------------------------
__global__ void out_proj(const float* __restrict__ hsum8, const float* __restrict__ Wfc,
                         const float* __restrict__ bfc, float* __restrict__ out) {
  const int t = blockIdx.x, tid = threadIdx.x;
  float a[10] = {0.f, 0.f, 0.f, 0.f, 0.f, 0.f, 0.f, 0.f, 0.f, 0.f};
  for (int col = tid; col < 400; col += 256) {
    const float* hb = hsum8 + ((size_t)t * 400 + col) * 8;
    float s = 0.f;
#pragma unroll
    for (int b = 0; b < 8; ++b) s += hb[b];
    const float hv = s * (1.f / 512.f);
#pragma unroll
    for (int o = 0; o < 10; ++o) a[o] = fmaf(hv, Wfc[o * 400 + col], a[o]);
  }
#pragma unroll
  for (int o = 0; o < 10; ++o) {
    float v = a[o];
    for (int m = 32; m; m >>= 1) v += __shfl_xor(v, m);
    a[o] = v;
  }
  __shared__ float red[4][10];
  if ((tid & 63) == 0)
#pragma unroll
    for (int o = 0; o < 10; ++o) red[tid >> 6][o] = a[o];
  __syncthreads();
  if (tid < 10)
    out[t * 10 + tid] = bfc[tid] + red[0][tid] + red[1][tid] + red[2][tid] + red[3][tid];
}

extern "C" void kernel_launch(void* const* d_in, const int* in_sizes, int n_in,
                              void* d_out, int out_size, void* d_ws, size_t ws_size,
                              hipStream_t stream) {
  const float* x     = (const float*)d_in[0];
  const float* W_in  = (const float*)d_in[1];
  const float* b_in  = (const float*)d_in[2];
  const float* Wih_f = (const float*)d_in[3];
  const float* Whh_f = (const float*)d_in[4];
  const float* b_f   = (const float*)d_in[5];
  const float* Wih_b = (const float*)d_in[6];
  const float* Whh_b = (const float*)d_in[7];
  const float* b_b   = (const float*)d_in[8];
  const float* W_fc  = (const float*)d_in[9];
  const float* b_fc  = (const float*)d_in[10];
  float* out = (float*)d_out;

  char* ws = (char*)d_ws;
  float*    hsum8 = (float*)(ws + WS_HSUM);
  float*    uv_g  = (float*)(ws + WS_UV);
  ushort_t* w_sw  = (ushort_t*)(ws + WS_WSW);

  hipFuncSetAttribute((const void*)lstm_main,
                      hipFuncAttributeMaxDynamicSharedMemorySize, DYN_LDS);

  hipMemsetAsync(hsum8, 0, (size_t)HS8_FLOATS * sizeof(float), stream);
  prep_uv<<<2, 256, 0, stream>>>(Wih_f, b_f, Wih_b, b_b, W_in, b_in, uv_g);
  prep_w<<<2 * NMT * NKT, 64, 0, stream>>>(Whh_f, Whh_b, uv_g, w_sw);
  lstm_main<<<64, THREADS, DYN_LDS, stream>>>(x, w_sw, hsum8);
  out_proj<<<T_STEPS, 256, 0, stream>>>(hsum8, W_fc, b_fc, out);
}

// Round 13
// 1636.078 us; speedup vs baseline: 13.7457x; 1.1039x over previous
//
#include <hip/hip_runtime.h>

// ---------------------------------------------------------------------------
// BiLSTM (T=784, B=512, H=200, D=1) on MI355X — round 13.
//
// Rounds 2-12 ledger: weight streaming (r3) == LDS+AGPR residency (r10) ==
// decontended atomics (r11) == stripped VALU (r12) ~= 1800us. Fixed serial
// per-step cost, insensitive to the instruction stream. The invariant all
// rounds shared: __syncthreads drains vmcnt(0) each step, forcing the
// deferred cross-XCD atomic RMWs to RETIRE before the barrier (~thousands
// of cycles of line-migration latency, FIFO-serialized). Round 13 removes
// global-memory completion from the step critical path:
//  1) atomics -> plain f32 stores to BLOCK-PRIVATE lines hpart[t][blk][200]
//     (no RMW, no cross-XCD sharing); out_proj reduces 32 slices.
//  2) barrier = inline-asm "s_waitcnt lgkmcnt(0); s_barrier" — LDS-only
//     ordering (h exchange needs only ds completion); stores stay in flight
//     across barriers (T4 discipline applied to stores).
//  3) x-slot write moved to end of step (x-load latency hidden).
// Step body (AGPR pins a0..a111, one 28-MFMA asm block, LDS-tile asm MFMAs,
// cell_update) byte-identical to r12.
// ---------------------------------------------------------------------------

typedef short short8 __attribute__((ext_vector_type(8)));
typedef float f32x4 __attribute__((ext_vector_type(4)));
typedef unsigned short ushort_t;

#define T_STEPS 784
#define BATCH   512
#define HID     200
#define NKT     7
#define NMT     50
#define THREADS 512
#define HBUF    3584
#define NLDST   18
#define DYN_LDS (2 * HBUF * 2 + NLDST * NKT * 512 * 2)  // 143360 B

// ws layout (bytes)
#define HPART_FLOATS ((size_t)T_STEPS * 64 * 200)       // 10,035,200 floats
#define WS_HPART 0                                       // 40,140,800 B
#define WS_UV    (40140800)                              // 12,800 B
#define WS_WSW   (40140800 + 12800)                      // 716,800 B

#define ACLOB \
  "a0","a1","a2","a3","a4","a5","a6","a7","a8","a9","a10","a11","a12","a13", \
  "a14","a15","a16","a17","a18","a19","a20","a21","a22","a23","a24","a25",   \
  "a26","a27","a28","a29","a30","a31","a32","a33","a34","a35","a36","a37",   \
  "a38","a39","a40","a41","a42","a43","a44","a45","a46","a47","a48","a49",   \
  "a50","a51","a52","a53","a54","a55","a56","a57","a58","a59","a60","a61",   \
  "a62","a63","a64","a65","a66","a67","a68","a69","a70","a71","a72","a73",   \
  "a74","a75","a76","a77","a78","a79","a80","a81","a82","a83","a84","a85",   \
  "a86","a87","a88","a89","a90","a91","a92","a93","a94","a95","a96","a97",   \
  "a98","a99","a100","a101","a102","a103","a104","a105","a106","a107",       \
  "a108","a109","a110","a111"

__device__ __forceinline__ ushort_t f2bf(float f) {
  union { float f; unsigned u; } x; x.f = f;
  return (ushort_t)((x.u + 0x7FFFu + ((x.u >> 16) & 1u)) >> 16);  // RNE
}
__device__ __forceinline__ float bf2f(ushort_t u) {
  union { unsigned u; float f; } x; x.u = (unsigned)u << 16; return x.f;
}

__device__ __forceinline__ float row16_sum(float v) {
  union { float f; int i; } a, b;
  a.f = v;
  b.i = __builtin_amdgcn_update_dpp(0, a.i, 0x118, 0xF, 0xF, true); a.f += b.f;
  b.i = __builtin_amdgcn_update_dpp(0, a.i, 0x114, 0xF, 0xF, true); a.f += b.f;
  b.i = __builtin_amdgcn_update_dpp(0, a.i, 0x112, 0xF, 0xF, true); a.f += b.f;
  b.i = __builtin_amdgcn_update_dpp(0, a.i, 0x111, 0xF, 0xF, true); a.f += b.f;
  return a.f;  // row sum valid at bcol==15
}

// --- AGPR pin: one 4-dword fragment of tile T, k-tile K into fixed a-regs
#define PIN1(T, K, N0, N1, N2, N3)                                            \
  {                                                                           \
    union { short8 s; unsigned u[4]; } cv;                                    \
    cv.s = *(const short8*)(wg +                                              \
        ((size_t)((rbase + (T)) * NKT + (K))) * 512 + lane * 8);              \
    asm volatile("v_accvgpr_write_b32 a" #N0 ", %0\n\t"                       \
                 "v_accvgpr_write_b32 a" #N1 ", %1\n\t"                       \
                 "v_accvgpr_write_b32 a" #N2 ", %2\n\t"                       \
                 "v_accvgpr_write_b32 a" #N3 ", %3"                           \
                 :: "v"(cv.u[0]), "v"(cv.u[1]), "v"(cv.u[2]), "v"(cv.u[3])    \
                 : "a" #N0, "a" #N1, "a" #N2, "a" #N3);                       \
  }

// ---------------------------------------------------------------------------
__global__ void prep_uv(const float* __restrict__ Wih_f, const float* __restrict__ b_f,
                        const float* __restrict__ Wih_b, const float* __restrict__ b_b,
                        const float* __restrict__ W_in, const float* __restrict__ b_in,
                        float* __restrict__ uv_g) {
  const int dir = blockIdx.x, j = threadIdx.x;
  if (j >= HID) return;
  const float* Wih = dir ? Wih_b : Wih_f;
  const float* b   = dir ? b_b   : b_f;
  for (int q = 0; q < 4; ++q) {
    const int row = q * HID + j;
    const float* wr = Wih + (size_t)row * HID;
    float u = 0.f, v = 0.f;
    for (int k = 0; k < HID; ++k) {
      u = fmaf(wr[k], W_in[k], u);
      v = fmaf(wr[k], b_in[k], v);
    }
    uv_g[(size_t)dir * 1600 + j * 8 + q]     = u;
    uv_g[(size_t)dir * 1600 + j * 8 + 4 + q] = v + b[row];
  }
}

// ---------------------------------------------------------------------------
__global__ void prep_w(const float* __restrict__ Whh_f, const float* __restrict__ Whh_b,
                       const float* __restrict__ uv_g, ushort_t* __restrict__ w_sw) {
  const int bid = blockIdx.x, lane = threadIdx.x;
  const int dir = bid / (NMT * NKT);
  const int rem = bid % (NMT * NKT);
  const int mt = rem / NKT, kt = rem % NKT;
  const float* W = dir ? Whh_b : Whh_f;
  const int m = lane & 15;
  const int q = m & 3;
  const int j = mt * 4 + (m >> 2);
  const int row = q * HID + j;
  const int grp = lane >> 4;
  short8 v8 = {0, 0, 0, 0, 0, 0, 0, 0};
  if (kt < 6) {
#pragma unroll
    for (int e = 0; e < 8; ++e)
      v8[e] = (short)f2bf(W[(size_t)row * HID + kt * 32 + grp * 8 + e]);
  } else if (grp == 0) {
#pragma unroll
    for (int e = 0; e < 8; ++e)
      v8[e] = (short)f2bf(W[(size_t)row * HID + 192 + e]);
  } else if (grp == 1) {
    const float U = uv_g[(size_t)dir * 1600 + j * 8 + q];
    const float V = uv_g[(size_t)dir * 1600 + j * 8 + 4 + q];
    const ushort_t vhi = f2bf(V), uhi = f2bf(U);
    v8[0] = (short)vhi;
    v8[1] = (short)f2bf(V - bf2f(vhi));
    v8[2] = (short)uhi;
    v8[3] = (short)f2bf(U - bf2f(uhi));
    v8[4] = (short)uhi;
  }
  *(short8*)(w_sw + (size_t)bid * 512 + (size_t)lane * 8) = v8;
}

// ---------------------------------------------------------------------------
__device__ __forceinline__ void cell_update(const f32x4 a, const int haddr,
                                            ushort_t* __restrict__ hnext,
                                            float& c, float& hold) {
  const float L1 = 1.44269504088896340736f;
  const float ei = __builtin_amdgcn_exp2f(fminf(-L1 * a[0], 30.f));
  const float ef = __builtin_amdgcn_exp2f(fminf(-L1 * a[1], 30.f));
  const float eg = __builtin_amdgcn_exp2f(fminf(-2.f * L1 * a[2], 30.f));
  const float eo = __builtin_amdgcn_exp2f(fminf(-L1 * a[3], 30.f));
  const float pi = 1.f + ei, pf = 1.f + ef, pg = 1.f + eg;
  const float pig = pi * pg;
  const float R1 = __builtin_amdgcn_rcpf(pig * pf);
  const float sf = pig * R1;
  const float sitg = (1.f - eg) * pf * R1;
  const float cn = fmaf(sf, c, sitg);
  c = cn;
  const float ec = __builtin_amdgcn_exp2f(fminf(-2.f * L1 * cn, 83.f));
  const float R2 = __builtin_amdgcn_rcpf((1.f + ec) * (1.f + eo));
  const float h = (1.f - ec) * R2;
  hnext[haddr] = f2bf(h);
  hold = row16_sum(h);
}

// ---------------------------------------------------------------------------
// 784-step scan: 4 AGPR tiles (a0..a111) at rbase.., NLDS LDS tiles at lfirst.
// Per-step hsum partials -> plain stores to block-private hpart lines.
// In-loop barrier waits lgkmcnt only (stores drift across barriers).
// ---------------------------------------------------------------------------
template <int NLDS>
__device__ __forceinline__ void scan_loop(
    const int rbase, const int lfirst, const int dir, const int b0,
    const int lane, const int wv, const int blk, const ushort_t* __restrict__ wg,
    const float* __restrict__ x, float* __restrict__ hpart,
    ushort_t* __restrict__ h_lds, const ushort_t* __restrict__ w_lds_my) {
  constexpr int NREG = 4;
  constexpr int NT = NREG + NLDS;
  const int bcol = lane & 15, krow = lane >> 4;
  const bool xw = (wv == 0) & (krow == 1);

  // pin 4 tiles into fixed AGPRs a0..a111 (28 dwords per tile)
  PIN1(0, 0,  0,  1,  2,  3)  PIN1(0, 1,  4,  5,  6,  7)
  PIN1(0, 2,  8,  9, 10, 11)  PIN1(0, 3, 12, 13, 14, 15)
  PIN1(0, 4, 16, 17, 18, 19)  PIN1(0, 5, 20, 21, 22, 23)
  PIN1(0, 6, 24, 25, 26, 27)
  PIN1(1, 0, 28, 29, 30, 31)  PIN1(1, 1, 32, 33, 34, 35)
  PIN1(1, 2, 36, 37, 38, 39)  PIN1(1, 3, 40, 41, 42, 43)
  PIN1(1, 4, 44, 45, 46, 47)  PIN1(1, 5, 48, 49, 50, 51)
  PIN1(1, 6, 52, 53, 54, 55)
  PIN1(2, 0, 56, 57, 58, 59)  PIN1(2, 1, 60, 61, 62, 63)
  PIN1(2, 2, 64, 65, 66, 67)  PIN1(2, 3, 68, 69, 70, 71)
  PIN1(2, 4, 72, 73, 74, 75)  PIN1(2, 5, 76, 77, 78, 79)
  PIN1(2, 6, 80, 81, 82, 83)
  PIN1(3, 0, 84, 85, 86, 87)  PIN1(3, 1, 88, 89, 90, 91)
  PIN1(3, 2, 92, 93, 94, 95)  PIN1(3, 3, 96, 97, 98, 99)
  PIN1(3, 4, 100, 101, 102, 103)  PIN1(3, 5, 104, 105, 106, 107)
  PIN1(3, 6, 108, 109, 110, 111)
  asm volatile("s_nop 7\n\ts_nop 7");  // accvgpr_write -> mfma-read spacing

  // persistent zero quad (C operand for every chain's first MFMA)
  f32x4 zero4 = {0.f, 0.f, 0.f, 0.f};
  asm volatile("" : "+v"(zero4));

  int haddr[NT];
#pragma unroll
  for (int i = 0; i < NT; ++i) {
    const int tile = (i < NREG) ? rbase + i : lfirst + (i - NREG);
    const int j = tile * 4 + krow;
    haddr[i] = (j >> 5) * 512 + (bcol | (((j >> 3) & 3) << 4)) * 8 + (j & 7);
  }
  float c[NT], hold[NT];
#pragma unroll
  for (int i = 0; i < NT; ++i) { c[i] = 0.f; hold[i] = 0.f; }

  const int jb = rbase * 4 + krow;
  const int jl = lfirst * 4 + krow;
  int t_prev = 0, cur = 0;

  for (int s = 0; s < T_STEPS; ++s) {
    const int t = dir ? (T_STEPS - 1 - s) : s;

    // B-fragments of [h(t-1); 1; x(t)] — issue LDS loads first
    short8 bf[NKT];
#pragma unroll
    for (int kt = 0; kt < NKT; ++kt)
      bf[kt] = *(const short8*)&h_lds[cur * HBUF + kt * 512 + lane * 8];

    // x for step s+1 (issued early; used at end of step)
    const int sn = (s + 1 < T_STEPS) ? s + 1 : s;
    float xn = 0.f;
    if (xw) xn = x[(size_t)(dir ? T_STEPS - 1 - sn : sn) * BATCH + b0 + bcol];

    // previous step's batch-partials: plain stores to block-private lines.
    // No reader until kernel end -> never forces a vmcnt drain at barriers.
    if (s > 0 && bcol == 15) {
      float* hp = hpart + ((size_t)t_prev * 64 + blk) * 200;
#pragma unroll
      for (int i = 0; i < NREG; ++i) hp[jb + 4 * i] = hold[i];
#pragma unroll
      for (int i = 0; i < NLDS; ++i) hp[jl + 4 * i] = hold[NREG + i];
    }

    ushort_t* hnext = h_lds + (cur ^ 1) * HBUF;

    // ---- AGPR region: ONE asm block, 28 MFMAs, 4 chains interleaved ----
    f32x4 a0, a1, a2, a3;
    asm volatile(
      "s_nop 1\n\t"
      "v_mfma_f32_16x16x32_bf16 %0, a[0:3],    %4, %11\n\t"
      "v_mfma_f32_16x16x32_bf16 %1, a[28:31],  %4, %11\n\t"
      "v_mfma_f32_16x16x32_bf16 %2, a[56:59],  %4, %11\n\t"
      "v_mfma_f32_16x16x32_bf16 %3, a[84:87],  %4, %11\n\t"
      "v_mfma_f32_16x16x32_bf16 %0, a[4:7],    %5, %0\n\t"
      "v_mfma_f32_16x16x32_bf16 %1, a[32:35],  %5, %1\n\t"
      "v_mfma_f32_16x16x32_bf16 %2, a[60:63],  %5, %2\n\t"
      "v_mfma_f32_16x16x32_bf16 %3, a[88:91],  %5, %3\n\t"
      "v_mfma_f32_16x16x32_bf16 %0, a[8:11],   %6, %0\n\t"
      "v_mfma_f32_16x16x32_bf16 %1, a[36:39],  %6, %1\n\t"
      "v_mfma_f32_16x16x32_bf16 %2, a[64:67],  %6, %2\n\t"
      "v_mfma_f32_16x16x32_bf16 %3, a[92:95],  %6, %3\n\t"
      "v_mfma_f32_16x16x32_bf16 %0, a[12:15],  %7, %0\n\t"
      "v_mfma_f32_16x16x32_bf16 %1, a[40:43],  %7, %1\n\t"
      "v_mfma_f32_16x16x32_bf16 %2, a[68:71],  %7, %2\n\t"
      "v_mfma_f32_16x16x32_bf16 %3, a[96:99],  %7, %3\n\t"
      "v_mfma_f32_16x16x32_bf16 %0, a[16:19],  %8, %0\n\t"
      "v_mfma_f32_16x16x32_bf16 %1, a[44:47],  %8, %1\n\t"
      "v_mfma_f32_16x16x32_bf16 %2, a[72:75],  %8, %2\n\t"
      "v_mfma_f32_16x16x32_bf16 %3, a[100:103],%8, %3\n\t"
      "v_mfma_f32_16x16x32_bf16 %0, a[20:23],  %9, %0\n\t"
      "v_mfma_f32_16x16x32_bf16 %1, a[48:51],  %9, %1\n\t"
      "v_mfma_f32_16x16x32_bf16 %2, a[76:79],  %9, %2\n\t"
      "v_mfma_f32_16x16x32_bf16 %3, a[104:107],%9, %3\n\t"
      "v_mfma_f32_16x16x32_bf16 %0, a[24:27],  %10, %0\n\t"
      "v_mfma_f32_16x16x32_bf16 %1, a[52:55],  %10, %1\n\t"
      "v_mfma_f32_16x16x32_bf16 %2, a[80:83],  %10, %2\n\t"
      "v_mfma_f32_16x16x32_bf16 %3, a[108:111],%10, %3\n\t"
      "s_nop 7\n\ts_nop 7"
      : "=&v"(a0), "=&v"(a1), "=&v"(a2), "=&v"(a3)
      : "v"(bf[0]), "v"(bf[1]), "v"(bf[2]), "v"(bf[3]), "v"(bf[4]),
        "v"(bf[5]), "v"(bf[6]), "v"(zero4)
      : ACLOB);
    cell_update(a0, haddr[0], hnext, c[0], hold[0]);
    cell_update(a1, haddr[1], hnext, c[1], hold[1]);
    cell_update(a2, haddr[2], hnext, c[2], hold[2]);
    cell_update(a3, haddr[3], hnext, c[3], hold[3]);

    // ---- LDS tiles: per-kt fused 2-MFMA asm, zero4 C at kt=0, nops in kt=6
#pragma unroll
    for (int p = 0; p + 1 < NLDS; p += 2) {
      const int i0 = NREG + p, i1 = NREG + p + 1;
      f32x4 b0r, b1r;
      {
        const short8 af0 = *(const short8*)&w_lds_my[((p)     * NKT + 0) * 512 + lane * 8];
        const short8 af1 = *(const short8*)&w_lds_my[((p + 1) * NKT + 0) * 512 + lane * 8];
        asm volatile("s_nop 1\n\t"
                     "v_mfma_f32_16x16x32_bf16 %0, %2, %4, %5\n\t"
                     "v_mfma_f32_16x16x32_bf16 %1, %3, %4, %5"
                     : "=&v"(b0r), "=&v"(b1r)
                     : "v"(af0), "v"(af1), "v"(bf[0]), "v"(zero4));
      }
#pragma unroll
      for (int kt = 1; kt < NKT - 1; ++kt) {
        const short8 af0 = *(const short8*)&w_lds_my[((p)     * NKT + kt) * 512 + lane * 8];
        const short8 af1 = *(const short8*)&w_lds_my[((p + 1) * NKT + kt) * 512 + lane * 8];
        asm volatile("v_mfma_f32_16x16x32_bf16 %0, %2, %4, %0\n\t"
                     "v_mfma_f32_16x16x32_bf16 %1, %3, %4, %1"
                     : "+v"(b0r), "+v"(b1r)
                     : "v"(af0), "v"(af1), "v"(bf[kt]));
      }
      {
        const short8 af0 = *(const short8*)&w_lds_my[((p)     * NKT + 6) * 512 + lane * 8];
        const short8 af1 = *(const short8*)&w_lds_my[((p + 1) * NKT + 6) * 512 + lane * 8];
        asm volatile("v_mfma_f32_16x16x32_bf16 %0, %2, %4, %0\n\t"
                     "v_mfma_f32_16x16x32_bf16 %1, %3, %4, %1\n\t"
                     "s_nop 7\n\ts_nop 7"
                     : "+v"(b0r), "+v"(b1r)
                     : "v"(af0), "v"(af1), "v"(bf[6]));
      }
      cell_update(b0r, haddr[i0], hnext, c[i0], hold[i0]);
      cell_update(b1r, haddr[i1], hnext, c[i1], hold[i1]);
    }
    if constexpr (NLDS & 1) {
      constexpr int p = NLDS - 1;
      const int i0 = NREG + p;
      f32x4 b0r;
      {
        const short8 af = *(const short8*)&w_lds_my[(p * NKT + 0) * 512 + lane * 8];
        asm volatile("s_nop 1\n\t"
                     "v_mfma_f32_16x16x32_bf16 %0, %1, %2, %3"
                     : "=&v"(b0r) : "v"(af), "v"(bf[0]), "v"(zero4));
      }
#pragma unroll
      for (int kt = 1; kt < NKT - 1; ++kt) {
        const short8 af = *(const short8*)&w_lds_my[(p * NKT + kt) * 512 + lane * 8];
        asm volatile("v_mfma_f32_16x16x32_bf16 %0, %1, %2, %0"
                     : "+v"(b0r) : "v"(af), "v"(bf[kt]));
      }
      {
        const short8 af = *(const short8*)&w_lds_my[(p * NKT + 6) * 512 + lane * 8];
        asm volatile("v_mfma_f32_16x16x32_bf16 %0, %1, %2, %0\n\t"
                     "s_nop 7\n\ts_nop 7"
                     : "+v"(b0r) : "v"(af), "v"(bf[6]));
      }
      cell_update(b0r, haddr[i0], hnext, c[i0], hold[i0]);
    }

    // write next step's x into hnext slots LAST (x-load latency fully hidden)
    if (xw) {
      const ushort_t hi = f2bf(xn);
      const ushort_t lo = f2bf(xn - bf2f(hi));
      const int sb = 6 * 512 + lane * 8;
      hnext[sb + 2] = hi;
      hnext[sb + 3] = hi;
      hnext[sb + 4] = lo;
    }

    t_prev = t;
    // LDS-only barrier: drain ds ops, leave global stores in flight.
    asm volatile("s_waitcnt lgkmcnt(0)\n\ts_barrier" ::: "memory");
    cur ^= 1;
  }
  // final step's partials
  if (bcol == 15) {
    float* hp = hpart + ((size_t)t_prev * 64 + blk) * 200;
#pragma unroll
    for (int i = 0; i < NREG; ++i) hp[jb + 4 * i] = hold[i];
#pragma unroll
    for (int i = 0; i < NLDS; ++i) hp[jl + 4 * i] = hold[NREG + i];
  }
}

// ---------------------------------------------------------------------------
// main scan kernel: 64 blocks, 512 threads, 2 waves/SIMD (112 AGPR + ~110 VGPR)
// ---------------------------------------------------------------------------
__global__ __launch_bounds__(THREADS, 2) void lstm_main(
    const float* __restrict__ x, const ushort_t* __restrict__ w_sw,
    float* __restrict__ hpart) {
  extern __shared__ __align__(16) ushort_t dynlds[];
  ushort_t* h_lds = dynlds;
  ushort_t* w_lds = dynlds + 2 * HBUF;

  const int tid = threadIdx.x;
  const int lane = tid & 63;
  const int wv = tid >> 6;
  const int blk = blockIdx.x;
  const int dir = blk & 1;
  const int b0 = (blk >> 1) * 16;

  const ushort_t* wg = w_sw + (size_t)dir * NMT * NKT * 512;

  for (int i = tid; i < HBUF; i += THREADS) ((unsigned*)h_lds)[i] = 0;
  for (int i = tid; i < NLDST * NKT * 64; i += THREADS)
    *(short8*)&w_lds[(size_t)i * 8] =
        *(const short8*)(wg + (size_t)32 * NKT * 512 + (size_t)i * 8);
  __syncthreads();

  if (tid < 16) {
    const int t0 = dir ? T_STEPS - 1 : 0;
    const float x0 = x[(size_t)t0 * BATCH + b0 + tid];
    const ushort_t hi = f2bf(x0);
    const ushort_t lo = f2bf(x0 - bf2f(hi));
    const int sb = 6 * 512 + (16 + tid) * 8;
    h_lds[sb + 0] = 0x3F80; h_lds[sb + 1] = 0x3F80;
    h_lds[HBUF + sb + 0] = 0x3F80; h_lds[HBUF + sb + 1] = 0x3F80;
    h_lds[sb + 2] = hi; h_lds[sb + 3] = hi; h_lds[sb + 4] = lo;
  }
  __syncthreads();

  const int rbase = 4 * wv;
  const int lfirst = (wv < 6) ? (32 + 2 * wv) : (44 + 3 * (wv - 6));
  const ushort_t* wl = w_lds + (size_t)(lfirst - 32) * NKT * 512;
  if (wv < 6)
    scan_loop<2>(rbase, lfirst, dir, b0, lane, wv, blk, wg, x, hpart, h_lds, wl);
  else
    scan_loop<3>(rbase, lfirst, dir, b0, lane, wv, blk, wg, x, hpart, h_lds, wl);
}

// ---------------------------------------------------------------------------
// out[t][o] = b_fc[o] + (1/512)*sum_col (sum_slice hpart[t][blk][j])*W_fc[o][col]
//   col = dir*200 + j; blk = (slice<<1)|dir. grid 784 x 256.
// ---------------------------------------------------------------------------
__global__ void out_proj(const float* __restrict__ hpart, const float* __restrict__ Wfc,
                         const float* __restrict__ bfc, float* __restrict__ out) {
  const int t = blockIdx.x, tid = threadIdx.x;
  const float* hb = hpart + (size_t)t * 64 * 200;
  float a[10] = {0.f, 0.f, 0.f, 0.f, 0.f, 0.f, 0.f, 0.f, 0.f, 0.f};
  for (int col = tid; col < 400; col += 256) {
    const int dir = (col >= HID) ? 1 : 0;
    const int j = col - dir * HID;
    float s = 0.f;
#pragma unroll
    for (int sl = 0; sl < 32; ++sl) s += hb[(size_t)((sl << 1) | dir) * 200 + j];
    const float hv = s * (1.f / 512.f);
#pragma unroll
    for (int o = 0; o < 10; ++o) a[o] = fmaf(hv, Wfc[o * 400 + col], a[o]);
  }
#pragma unroll
  for (int o = 0; o < 10; ++o) {
    float v = a[o];
    for (int m = 32; m; m >>= 1) v += __shfl_xor(v, m);
    a[o] = v;
  }
  __shared__ float red[4][10];
  if ((tid & 63) == 0)
#pragma unroll
    for (int o = 0; o < 10; ++o) red[tid >> 6][o] = a[o];
  __syncthreads();
  if (tid < 10)
    out[t * 10 + tid] = bfc[tid] + red[0][tid] + red[1][tid] + red[2][tid] + red[3][tid];
}

extern "C" void kernel_launch(void* const* d_in, const int* in_sizes, int n_in,
                              void* d_out, int out_size, void* d_ws, size_t ws_size,
                              hipStream_t stream) {
  const float* x     = (const float*)d_in[0];
  const float* W_in  = (const float*)d_in[1];
  const float* b_in  = (const float*)d_in[2];
  const float* Wih_f = (const float*)d_in[3];
  const float* Whh_f = (const float*)d_in[4];
  const float* b_f   = (const float*)d_in[5];
  const float* Wih_b = (const float*)d_in[6];
  const float* Whh_b = (const float*)d_in[7];
  const float* b_b   = (const float*)d_in[8];
  const float* W_fc  = (const float*)d_in[9];
  const float* b_fc  = (const float*)d_in[10];
  float* out = (float*)d_out;

  char* ws = (char*)d_ws;
  float*    hpart = (float*)(ws + WS_HPART);
  float*    uv_g  = (float*)(ws + WS_UV);
  ushort_t* w_sw  = (ushort_t*)(ws + WS_WSW);

  hipFuncSetAttribute((const void*)lstm_main,
                      hipFuncAttributeMaxDynamicSharedMemorySize, DYN_LDS);

  prep_uv<<<2, 256, 0, stream>>>(Wih_f, b_f, Wih_b, b_b, W_in, b_in, uv_g);
  prep_w<<<2 * NMT * NKT, 64, 0, stream>>>(Whh_f, Whh_b, uv_g, w_sw);
  lstm_main<<<64, THREADS, DYN_LDS, stream>>>(x, w_sw, hpart);
  out_proj<<<T_STEPS, 256, 0, stream>>>(hpart, W_fc, b_fc, out);
}